// Round 9
// baseline (192.873 us; speedup 1.0000x reference)
//
#include <hip/hip_runtime.h>
#include <cmath>

// MemoryEfficientAttention: x[2,2048,1024] -> qkv -> 16-head attn -> proj.
// Round 16: attention v11 = K register-direct. The K A-frag pattern
// (row=t*16+k15, chunk=quad) is a perfectly coalesced global read of
// k16[key][dh], so K skips LDS entirely: no K staging, no K LDS traffic,
// no barrier dependency for K (loads sit in vmcnt, hidden by TLP).
// V keeps the LDS dbuf path (transposed layout). LDS 64->34KB.
// Requires L2 residency: XCD head-affinity block swizzle (bid&7 selects
// XCD; all 16 q-blocks of one (h,b) land on one XCD -> 4 pairs x 512KB
// = 2MB per 4MB L2). GEMMs unchanged from R8.

namespace {
constexpr int kDim   = 1024;
constexpr int kHeads = 16;
constexpr int kHd    = 64;
constexpr int kB     = 2;
constexpr int kN     = 2048;
constexpr int kM     = kB * kN;
constexpr float kScale  = 0.125f;                       // 1/sqrt(64)
constexpr float kQScale = 0.125f * 1.44269504088896f;   // fold log2(e)
constexpr int kP = 72;              // padded LDS stride (qkv-T bounce / path C)
}  // namespace

typedef __attribute__((ext_vector_type(8))) short bf16x8;
typedef __attribute__((ext_vector_type(4))) float f32x4;

#if __has_builtin(__builtin_amdgcn_exp2f)
#define EXP2(x) __builtin_amdgcn_exp2f(x)
#else
#define EXP2(x) __expf((x) * 0.6931471805599453f)
#endif

__device__ inline unsigned short f2bf(float x) {
  union { float f; unsigned u; } un; un.f = x;
  unsigned r = un.u + 0x7fffu + ((un.u >> 16) & 1u);   // RNE
  return (unsigned short)(r >> 16);
}
__device__ inline unsigned pack2bf(float x, float y) {
  return (unsigned)f2bf(x) | ((unsigned)f2bf(y) << 16);
}
__device__ inline void gl_lds16(const short* g, short* l) {
  __builtin_amdgcn_global_load_lds(
      (const __attribute__((address_space(1))) unsigned*)g,
      (__attribute__((address_space(3))) unsigned*)l, 16, 0, 0);
}

// ---------------------------------------------------------------------------
// Merged fp32->bf16 convert: blocks [0,n0) -> a, [n0,n0+n1) -> b, rest -> c.
__global__ __launch_bounds__(256) void cvt3_kernel(
    const float* __restrict__ a, short* __restrict__ da, int n0,
    const float* __restrict__ b, short* __restrict__ db, int n1,
    const float* __restrict__ c, short* __restrict__ dc) {
  int blk = blockIdx.x;
  const float* src; short* dst;
  if (blk < n0) { src = a; dst = da; }
  else if (blk < n0 + n1) { src = b; dst = db; blk -= n0; }
  else { src = c; dst = dc; blk -= n0 + n1; }
  const int i = (blk * 256 + threadIdx.x) * 8;
  float4 u = *(const float4*)&src[i];
  float4 v = *(const float4*)&src[i + 4];
  bf16x8 o = {(short)f2bf(u.x), (short)f2bf(u.y), (short)f2bf(u.z), (short)f2bf(u.w),
              (short)f2bf(v.x), (short)f2bf(v.y), (short)f2bf(v.z), (short)f2bf(v.w)};
  *(bf16x8*)&dst[i] = o;
}

// ---------------------------------------------------------------------------
// QKV GEMM (path A): A16[4096,1024] @ W16[3072,1024]^T. 128x128 tile, BK=64,
// global_load_lds + XOR swizzle, 2-phase prefetch (dbuf LDS, stage(next)
// before compute(cur), one __syncthreads per K-tile). Epilogue: Q scaled by
// kQScale -> [b][h][n][dh]; K -> [b][h][n][dh]; V -> TRANSPOSED [b][h][dh][n].
__global__ __launch_bounds__(256, 2) void mm_qkv_kernel(
    const short* __restrict__ A16, const short* __restrict__ W16,
    short* __restrict__ q16, short* __restrict__ k16, short* __restrict__ vT16) {
  __shared__ short smem[2 * 2 * 128 * 64];   // 64 KiB: [buf][A|B][128][64]
  const int tid  = threadIdx.x;
  const int w    = tid >> 6;
  const int lane = tid & 63;
  const int quad = lane >> 4;
  const int k15  = lane & 15;
  const int m0   = blockIdx.x * 128;
  const int seg  = blockIdx.y >> 3;
  const int nt0  = (blockIdx.y & 7) << 7;
  const int wrow0 = seg * 1024 + nt0;
  const int wm = (w >> 1) * 64;
  const int wn = (w & 1) * 64;
  const int lrow   = lane >> 3;
  const int lchunk = (lane & 7) ^ lrow;

  f32x4 acc[4][4];
#pragma unroll
  for (int i = 0; i < 4; ++i)
#pragma unroll
    for (int j = 0; j < 4; ++j) acc[i][j] = (f32x4){0.f, 0.f, 0.f, 0.f};

  auto stage = [&](int kt, int buf) {
    short* As = smem + buf * 16384;
    short* Bs = As + 8192;
    const int koff = kt * 64;
#pragma unroll
    for (int p = 0; p < 4; ++p) {
      const int r0 = p * 32 + w * 8;
      gl_lds16(&A16[(long)(m0 + r0 + lrow) * 1024 + koff + lchunk * 8], &As[r0 * 64]);
      gl_lds16(&W16[(long)(wrow0 + r0 + lrow) * 1024 + koff + lchunk * 8], &Bs[r0 * 64]);
    }
  };

  stage(0, 0);
  __syncthreads();
  for (int kt = 0; kt < 16; ++kt) {
    if (kt + 1 < 16) stage(kt + 1, (kt + 1) & 1);   // prefetch under compute
    const short* As = smem + (kt & 1) * 16384;
    const short* Bs = As + 8192;
#pragma unroll
    for (int ks = 0; ks < 2; ++ks) {
      bf16x8 af[4], bf[4];
#pragma unroll
      for (int t = 0; t < 4; ++t) {
        const int Ra = wm + t * 16 + k15;
        af[t] = *(const bf16x8*)&As[Ra * 64 + (((ks << 2) + quad) ^ (Ra & 7)) * 8];
        const int Rb = wn + t * 16 + k15;
        bf[t] = *(const bf16x8*)&Bs[Rb * 64 + (((ks << 2) + quad) ^ (Rb & 7)) * 8];
      }
#pragma unroll
      for (int mt = 0; mt < 4; ++mt)
#pragma unroll
        for (int nt = 0; nt < 4; ++nt)
          acc[mt][nt] = __builtin_amdgcn_mfma_f32_16x16x32_bf16(
              af[mt], bf[nt], acc[mt][nt], 0, 0, 0);
    }
    __syncthreads();
  }

  if (seg < 2) {
    short* dst = (seg == 0) ? q16 : k16;
    const float sc = (seg == 0) ? kQScale : 1.0f;
#pragma unroll
    for (int nt = 0; nt < 4; ++nt) {
      const int dl = nt0 + wn + nt * 16 + k15;
      const int h  = dl >> 6;
      const int dh = dl & 63;
#pragma unroll
      for (int mt = 0; mt < 4; ++mt) {
#pragma unroll
        for (int r = 0; r < 4; ++r) {
          const int ml = m0 + wm + mt * 16 + quad * 4 + r;
          const int b  = ml >> 11;
          const int n  = ml & 2047;
          dst[(((long)(b * kHeads + h) * kN) + n) * kHd + dh] =
              (short)f2bf(acc[mt][nt][r] * sc);
        }
      }
    }
  } else {
    __syncthreads();
    short* Tw = smem + w * 16 * kP;
#pragma unroll
    for (int nt = 0; nt < 4; ++nt) {
#pragma unroll
      for (int mt = 0; mt < 4; ++mt) {
        uint2 pk;
        pk.x = pack2bf(acc[mt][nt][0], acc[mt][nt][1]);
        pk.y = pack2bf(acc[mt][nt][2], acc[mt][nt][3]);
        *(uint2*)&Tw[k15 * kP + mt * 16 + quad * 4] = pk;
      }
#pragma unroll
      for (int i = 0; i < 2; ++i) {
        const int idx  = i * 64 + lane;
        const int trow = idx >> 3;
        const int tch  = idx & 7;
        bf16x8 row = *(const bf16x8*)&Tw[trow * kP + tch * 8];
        const int vcol = nt0 + wn + nt * 16 + trow;
        const int h  = vcol >> 6;
        const int dh = vcol & 63;
        const int m  = m0 + wm + tch * 8;
        const int b  = m >> 11;
        const int n  = m & 2047;
        *(bf16x8*)&vT16[(((long)(b * kHeads + h) * kHd) + dh) * kN + n] = row;
      }
    }
  }
}

// ---------------------------------------------------------------------------
// proj GEMM: out = ao16[4096,1024] @ PW16[1024,1024]^T + bias (fp32 out).
// Same 2-phase prefetch structure as mm_qkv.
__global__ __launch_bounds__(256, 2) void mm_proj_kernel(
    const short* __restrict__ A16, const short* __restrict__ B16,
    const float* __restrict__ bias, float* __restrict__ out) {
  __shared__ short smem[2 * 2 * 128 * 64];   // 64 KiB: [buf][A|B][128][64]
  const int tid  = threadIdx.x;
  const int w    = tid >> 6;
  const int lane = tid & 63;
  const int quad = lane >> 4;
  const int k15  = lane & 15;
  const int m0 = blockIdx.x * 128;
  const int n0 = blockIdx.y * 128;
  const int wm = (w >> 1) * 64;
  const int wn = (w & 1) * 64;
  const int lrow   = lane >> 3;
  const int lchunk = (lane & 7) ^ lrow;

  f32x4 acc[4][4];
#pragma unroll
  for (int i = 0; i < 4; ++i)
#pragma unroll
    for (int j = 0; j < 4; ++j) acc[i][j] = (f32x4){0.f, 0.f, 0.f, 0.f};

  auto stage = [&](int kt, int buf) {
    short* As = smem + buf * 16384;
    short* Bs = As + 8192;
    const int koff = kt * 64;
#pragma unroll
    for (int p = 0; p < 4; ++p) {
      const int r0 = p * 32 + w * 8;
      gl_lds16(&A16[(long)(m0 + r0 + lrow) * 1024 + koff + lchunk * 8], &As[r0 * 64]);
      gl_lds16(&B16[(long)(n0 + r0 + lrow) * 1024 + koff + lchunk * 8], &Bs[r0 * 64]);
    }
  };

  stage(0, 0);
  __syncthreads();
  for (int kt = 0; kt < 16; ++kt) {
    if (kt + 1 < 16) stage(kt + 1, (kt + 1) & 1);   // prefetch under compute
    const short* As = smem + (kt & 1) * 16384;
    const short* Bs = As + 8192;
#pragma unroll
    for (int ks = 0; ks < 2; ++ks) {
      bf16x8 af[4], bf[4];
#pragma unroll
      for (int t = 0; t < 4; ++t) {
        const int Ra = wm + t * 16 + k15;
        af[t] = *(const bf16x8*)&As[Ra * 64 + (((ks << 2) + quad) ^ (Ra & 7)) * 8];
        const int Rb = wn + t * 16 + k15;
        bf[t] = *(const bf16x8*)&Bs[Rb * 64 + (((ks << 2) + quad) ^ (Rb & 7)) * 8];
      }
#pragma unroll
      for (int mt = 0; mt < 4; ++mt)
#pragma unroll
        for (int nt = 0; nt < 4; ++nt)
          acc[mt][nt] = __builtin_amdgcn_mfma_f32_16x16x32_bf16(
              af[mt], bf[nt], acc[mt][nt], 0, 0, 0);
    }
    __syncthreads();
  }

#pragma unroll
  for (int nt = 0; nt < 4; ++nt) {
    const int d = n0 + wn + nt * 16 + k15;
    const float bb = bias[d];
#pragma unroll
    for (int mt = 0; mt < 4; ++mt) {
#pragma unroll
      for (int r = 0; r < 4; ++r) {
        const int m = m0 + wm + mt * 16 + quad * 4 + r;
        out[(long)m * 1024 + d] = acc[mt][nt][r] + bb;
      }
    }
  }
}

// ---------------------------------------------------------------------------
// Flash attention v11: block = 512 threads = 8 waves = {2 key-groups} x
// {4 q-subwaves}; wave = 32 q-rows (2 qt), 1024 keys in 16 x 64-key tiles.
// K is REGISTER-DIRECT from global (coalesced 16-row x 64B reads; no K LDS,
// no K staging, no barrier dependency for K — loads hide in vmcnt under TLP).
// V stays LDS double-buffered (transposed layout), stage(next) under
// compute(cur), one __syncthreads per tile. XCD head-affinity swizzle:
// bid&7 = XCD; all 16 q-blocks of one (h,b) land on one XCD -> per-XCD
// K/V working set = 4 pairs x 512KB = 2MB (fits 4MB L2).
// Swapped QK^T (mfma(K,Q)); P->A-frag in-register via cvt_pk_bf16 +
// permlane swaps; linear partial (O,L) merged in-block.
__global__ __launch_bounds__(512)
__attribute__((amdgpu_waves_per_eu(2, 4)))
void attn_kernel(
    const short* __restrict__ q16, const short* __restrict__ k16,
    const short* __restrict__ vT16, short* __restrict__ ao16) {
  // 34 KiB: V tiles [g][buf] (64 dh x 64 key, chunk-XOR swizzled) in
  // [0,32KB); merge slots (4 x 8704B) overlay the same region at the end.
  __shared__ __align__(16) short smem[17408];

  const int tid  = threadIdx.x;         // 0..511
  const int w    = tid >> 6;            // 0..7
  const int g    = w >> 2;              // key-group: 0 -> [0,1024), 1 -> [1024,2048)
  const int sw   = w & 3;               // q-subwave: rows [sw*32, sw*32+32)
  const int lane = tid & 63;
  const int quad = lane >> 4;
  const int k15  = lane & 15;
  const int lrow8 = lane >> 3;          // V staging: 8 rows x 8 chunks per call
  const int lch8  = lane & 7;

  // XCD head-affinity decode: consecutive block ids round-robin XCDs, so
  // bid&7 pins the XCD; (h,b) constant per (xcd, bid>>7) -> L2 residency.
  const int bid  = blockIdx.x;          // 0..511
  const int xcd  = bid & 7;
  const int jj   = bid >> 3;            // 0..63
  const int hb   = xcd + 8 * (jj >> 4); // 0..31, constant per XCD quarter
  const int h    = hb & 15;
  const int b    = hb >> 4;
  const int qblk = jj & 15;
  const long base = (long)(b * kHeads + h) * kN * kHd;

  // Q B-frags: 2 qt tiles (32 rows). Waves w and w+4 load the same rows.
  bf16x8 qf[2][2];
#pragma unroll
  for (int qt = 0; qt < 2; ++qt) {
    const long qr = base + (long)(qblk * 128 + sw * 32 + qt * 16 + k15) * kHd;
    qf[qt][0] = *(const bf16x8*)&q16[qr + quad * 8];
    qf[qt][1] = *(const bf16x8*)&q16[qr + 32 + quad * 8];
  }

  f32x4 accO[2][4];
#pragma unroll
  for (int qt = 0; qt < 2; ++qt)
#pragma unroll
    for (int d = 0; d < 4; ++d) accO[qt][d] = (f32x4){0.f, 0.f, 0.f, 0.f};
  float lacc[2] = {0.f, 0.f};

  const short* kg0 = k16 + base + (long)g * 1024 * kHd;
  const short* vg0 = vT16 + base + g * 1024;

  // Stage one 64-key V tile for this wave's group into buffer `buf`.
  auto stageV = [&](int kt, int buf) {
    const short* vg = vg0 + kt * 64;
    short* Vb = &smem[(g * 2 + buf) * 4096];
#pragma unroll
    for (int c = 0; c < 2; ++c) {       // V: 64 dh-rows x 128B, 4 waves/group
      const int r0 = sw * 16 + c * 8;
      gl_lds16(vg + (long)(r0 + lrow8) * kN + (lch8 ^ ((r0 + lrow8) & 7)) * 8,
               &Vb[r0 * 64]);
    }
  };

  // Compute one 64-key tile: K direct from global, V from LDS buffer `buf`.
  auto compute = [&](int kt, int buf) {
    const short* Kt = kg0 + (long)kt * 64 * kHd;
    const short* Vc = &smem[(g * 2 + buf) * 4096];

    // K A-frags direct from global: row t*16+k15, chunks quad / 4+quad.
    bf16x8 kb[4][2];
#pragma unroll
    for (int t = 0; t < 4; ++t) {
      const short* kr = Kt + (long)(t * 16 + k15) * kHd;
      kb[t][0] = *(const bf16x8*)&kr[quad * 8];
      kb[t][1] = *(const bf16x8*)&kr[32 + quad * 8];
    }

    // QK^T swapped: sc[qt][t] = S^T tile, col = q (k15), row = key (quad*4+r).
    f32x4 sc[2][4];
    __builtin_amdgcn_s_setprio(1);
#pragma unroll
    for (int t = 0; t < 4; ++t) {
      f32x4 z0 = {0.f, 0.f, 0.f, 0.f};
      z0 = __builtin_amdgcn_mfma_f32_16x16x32_bf16(kb[t][0], qf[0][0], z0, 0, 0, 0);
      z0 = __builtin_amdgcn_mfma_f32_16x16x32_bf16(kb[t][1], qf[0][1], z0, 0, 0, 0);
      sc[0][t] = z0;
      f32x4 z1 = {0.f, 0.f, 0.f, 0.f};
      z1 = __builtin_amdgcn_mfma_f32_16x16x32_bf16(kb[t][0], qf[1][0], z1, 0, 0, 0);
      z1 = __builtin_amdgcn_mfma_f32_16x16x32_bf16(kb[t][1], qf[1][1], z1, 0, 0, 0);
      sc[1][t] = z1;
    }
    __builtin_amdgcn_s_setprio(0);

    // exp2 + RNE pack to bf16 pairs; lane-local row-sum accumulation.
    unsigned pk[2][4][2];
#pragma unroll
    for (int qt = 0; qt < 2; ++qt) {
      float ls = 0.f;
#pragma unroll
      for (int t = 0; t < 4; ++t) {
        const float p0 = EXP2(sc[qt][t][0]);
        const float p1 = EXP2(sc[qt][t][1]);
        const float p2 = EXP2(sc[qt][t][2]);
        const float p3 = EXP2(sc[qt][t][3]);
        ls += (p0 + p1) + (p2 + p3);
        asm("v_cvt_pk_bf16_f32 %0, %1, %2" : "=v"(pk[qt][t][0]) : "v"(p0), "v"(p1));
        asm("v_cvt_pk_bf16_f32 %0, %1, %2" : "=v"(pk[qt][t][1]) : "v"(p2), "v"(p3));
      }
      lacc[qt] += ls;
    }

#pragma unroll
    for (int kc = 0; kc < 2; ++kc) {
      // Redistribute so lane (quad,q) holds keys kc*32 + quad*8 + {0..7}.
      union { unsigned u[4]; bf16x8 v; } pf[2];
#pragma unroll
      for (int qt = 0; qt < 2; ++qt) {
        unsigned a = pk[qt][2 * kc][0],     bq = pk[qt][2 * kc][1];
        unsigned c = pk[qt][2 * kc + 1][0], d4 = pk[qt][2 * kc + 1][1];
        asm("v_permlane32_swap_b32 %0, %1" : "+v"(a), "+v"(c));
        asm("v_permlane16_swap_b32 %0, %1" : "+v"(a), "+v"(c));
        asm("v_permlane32_swap_b32 %0, %1" : "+v"(bq), "+v"(d4));
        asm("v_permlane16_swap_b32 %0, %1" : "+v"(bq), "+v"(d4));
        pf[qt].u[0] = a; pf[qt].u[1] = bq; pf[qt].u[2] = c; pf[qt].u[3] = d4;
      }
      __builtin_amdgcn_s_setprio(1);
#pragma unroll
      for (int d = 0; d < 4; ++d) {
        const int vrow = d * 16 + k15;
        const int ch = (kc * 4 + quad) ^ (vrow & 7);
        bf16x8 vb = *(const bf16x8*)&Vc[vrow * 64 + ch * 8];
        accO[0][d] = __builtin_amdgcn_mfma_f32_16x16x32_bf16(pf[0].v, vb, accO[0][d], 0, 0, 0);
        accO[1][d] = __builtin_amdgcn_mfma_f32_16x16x32_bf16(pf[1].v, vb, accO[1][d], 0, 0, 0);
      }
      __builtin_amdgcn_s_setprio(0);
    }
  };

  stageV(0, 0);
  __syncthreads();
  for (int kt = 0; kt < 16; ++kt) {
    if (kt + 1 < 16) stageV(kt + 1, (kt + 1) & 1);   // prefetch V under compute
    compute(kt, kt & 1);
    __syncthreads();
  }

  // Per-wave partial row sums: lane (quad,q) holds 1/4 of its group's L[q].
  float s[2];
#pragma unroll
  for (int qt = 0; qt < 2; ++qt) {
    float v = lacc[qt];
    v += __shfl_xor(v, 16);
    v += __shfl_xor(v, 32);
    s[qt] = v;                      // L_partial[q = k15], replicated over quads
  }

  // In-block merge: group-1 waves publish (O, L) partials; group-0 adds,
  // normalizes, stores. Slot: 8 KiB accO + 512 B L per q-subwave.
  // The loop-final __syncthreads already fenced the last compute's V reads.
  {
    char* slot = (char*)smem + sw * 8704;
    f32x4* so = (f32x4*)slot;
    float* sl = (float*)(slot + 8192);
    if (w >= 4) {
#pragma unroll
      for (int qt = 0; qt < 2; ++qt) {
#pragma unroll
        for (int d = 0; d < 4; ++d) so[(qt * 4 + d) * 64 + lane] = accO[qt][d];
        sl[qt * 64 + lane] = s[qt];
      }
    }
    __syncthreads();
    if (w < 4) {
#pragma unroll
      for (int qt = 0; qt < 2; ++qt) {
        f32x4 am[4];
#pragma unroll
        for (int d = 0; d < 4; ++d)
          am[d] = accO[qt][d] + so[(qt * 4 + d) * 64 + lane];
        const float Lsum = s[qt] + sl[qt * 64 + lane];   // L[q=k15]
#pragma unroll
        for (int r = 0; r < 4; ++r) {
          const float Ls = __shfl(Lsum, quad * 4 + r);   // lanes 0..15 hold q
          const float in = 1.f / Ls;
          const int gq = qblk * 128 + sw * 32 + qt * 16 + quad * 4 + r;
          short* drow = ao16 + ((long)(b * kN + gq)) * kDim + h * kHd;
#pragma unroll
          for (int d = 0; d < 4; ++d)
            drow[d * 16 + k15] = (short)f2bf(am[d][r] * in);
        }
      }
    }
  }
}

// ---------------------------------------------------------------------------
// Path C fallback (proven r3-style, 20 MiB): fp32-input VGPR-staged kernels.
__global__ __launch_bounds__(256, 2) void r3_qkv_kernel(
    const float* __restrict__ X, const float* __restrict__ W,
    short* __restrict__ q16, short* __restrict__ k16, short* __restrict__ v16) {
  __shared__ short As[128 * kP];
  __shared__ short Ws[128 * kP];
  const int tid  = threadIdx.x;
  const int w    = tid >> 6;
  const int lane = tid & 63;
  const int quad = lane >> 4;
  const int k15  = lane & 15;
  const int m0 = blockIdx.x * 128;
  const int n0 = blockIdx.y * 128;
  const int wm = (w >> 1) * 64;
  const int wn = (w & 1) * 64;

  f32x4 acc[4][4];
#pragma unroll
  for (int i = 0; i < 4; ++i)
#pragma unroll
    for (int j = 0; j < 4; ++j) acc[i][j] = (f32x4){0.f, 0.f, 0.f, 0.f};

  for (int kt = 0; kt < kDim; kt += 64) {
    __syncthreads();
#pragma unroll
    for (int p = 0; p < 8; ++p) {
      const int idx = p * 256 + tid;
      const int row = idx >> 4;
      const int c4  = (idx & 15) << 2;
      float4 av = *(const float4*)&X[(long)(m0 + row) * kDim + kt + c4];
      uint2 ap = {pack2bf(av.x, av.y), pack2bf(av.z, av.w)};
      *(uint2*)&As[row * kP + c4] = ap;
      float4 wv = *(const float4*)&W[(long)(n0 + row) * kDim + kt + c4];
      uint2 wp = {pack2bf(wv.x, wv.y), pack2bf(wv.z, wv.w)};
      *(uint2*)&Ws[row * kP + c4] = wp;
    }
    __syncthreads();
#pragma unroll
    for (int ks = 0; ks < 2; ++ks) {
      bf16x8 af[4], bf[4];
#pragma unroll
      for (int t = 0; t < 4; ++t) {
        af[t] = *(const bf16x8*)&As[(wm + t * 16 + k15) * kP + ks * 32 + quad * 8];
        bf[t] = *(const bf16x8*)&Ws[(wn + t * 16 + k15) * kP + ks * 32 + quad * 8];
      }
#pragma unroll
      for (int mt = 0; mt < 4; ++mt)
#pragma unroll
        for (int nt = 0; nt < 4; ++nt)
          acc[mt][nt] = __builtin_amdgcn_mfma_f32_16x16x32_bf16(
              af[mt], bf[nt], acc[mt][nt], 0, 0, 0);
    }
  }

  const int t_sel = n0 >> 10;
  short* dst = (t_sel == 0) ? q16 : (t_sel == 1) ? k16 : v16;
  const float scl = (t_sel == 0) ? kScale : 1.0f;
#pragma unroll
  for (int nt = 0; nt < 4; ++nt) {
    const int d  = n0 + wn + nt * 16 + k15;
    const int h  = (d >> 6) & 15;
    const int dh = d & 63;
#pragma unroll
    for (int mt = 0; mt < 4; ++mt) {
#pragma unroll
      for (int r = 0; r < 4; ++r) {
        const int m = m0 + wm + mt * 16 + quad * 4 + r;
        dst[((long)h * kN + m) * kHd + dh] = (short)f2bf(acc[mt][nt][r] * scl);
      }
    }
  }
}

__global__ __launch_bounds__(256, 4) void attn_v1_kernel(
    const short* __restrict__ q16, const short* __restrict__ k16,
    const short* __restrict__ v16, short* __restrict__ ao16, int bpar) {
  __shared__ short Ks[64 * kP];
  __shared__ short Vs[64 * kP];
  __shared__ short Ps[4 * 16 * kP];
  const int tid  = threadIdx.x;
  const int w    = tid >> 6;
  const int lane = tid & 63;
  const int quad = lane >> 4;
  const int k15  = lane & 15;
  const long base = (long)blockIdx.y * kN * kHd;
  const int qrow = blockIdx.x * 64 + w * 16 + k15;
  const short* qp = q16 + base + (long)qrow * kHd + quad * 8;
  bf16x8 qf0 = *(const bf16x8*)(qp);
  bf16x8 qf1 = *(const bf16x8*)(qp + 32);

  f32x4 accO[4] = {{0.f,0.f,0.f,0.f},{0.f,0.f,0.f,0.f},
                   {0.f,0.f,0.f,0.f},{0.f,0.f,0.f,0.f}};
  float lsum[4] = {0.f, 0.f, 0.f, 0.f};

  for (int kt = 0; kt < kN / 64; ++kt) {
    __syncthreads();
    {
      const short* kg = k16 + base + (long)kt * 64 * kHd;
      const short* vg = v16 + base + (long)kt * 64 * kHd;
#pragma unroll
      for (int p = 0; p < 2; ++p) {
        const int idx = p * 256 + tid;
        const int key = idx >> 3;
        const int c8  = (idx & 7) << 3;
        *(bf16x8*)&Ks[key * kP + c8] = *(const bf16x8*)&kg[key * kHd + c8];
        bf16x8 vv = *(const bf16x8*)&vg[key * kHd + c8];
#pragma unroll
        for (int j = 0; j < 8; ++j) Vs[(c8 + j) * kP + key] = vv[j];
      }
    }
    __syncthreads();

    f32x4 sc[4];
#pragma unroll
    for (int t = 0; t < 4; ++t) {
      bf16x8 kb0 = *(const bf16x8*)&Ks[(t * 16 + k15) * kP + quad * 8];
      bf16x8 kb1 = *(const bf16x8*)&Ks[(t * 16 + k15) * kP + 32 + quad * 8];
      f32x4 z = {0.f, 0.f, 0.f, 0.f};
      z = __builtin_amdgcn_mfma_f32_16x16x32_bf16(qf0, kb0, z, 0, 0, 0);
      z = __builtin_amdgcn_mfma_f32_16x16x32_bf16(qf1, kb1, z, 0, 0, 0);
      sc[t] = z;
    }
    short* pw = &Ps[w * (16 * kP)];
#pragma unroll
    for (int t = 0; t < 4; ++t) {
#pragma unroll
      for (int r = 0; r < 4; ++r) {
        const float p = __expf(sc[t][r]);
        lsum[r] += p;
        pw[(quad * 4 + r) * kP + t * 16 + k15] = (short)f2bf(p);
      }
    }
    bf16x8 pf0 = *(const bf16x8*)&pw[k15 * kP + quad * 8];
    bf16x8 pf1 = *(const bf16x8*)&pw[k15 * kP + 32 + quad * 8];
#pragma unroll
    for (int t = 0; t < 4; ++t) {
      bf16x8 vb0 = *(const bf16x8*)&Vs[(t * 16 + k15) * kP + quad * 8];
      bf16x8 vb1 = *(const bf16x8*)&Vs[(t * 16 + k15) * kP + 32 + quad * 8];
      accO[t] = __builtin_amdgcn_mfma_f32_16x16x32_bf16(pf0, vb0, accO[t], 0, 0, 0);
      accO[t] = __builtin_amdgcn_mfma_f32_16x16x32_bf16(pf1, vb1, accO[t], 0, 0, 0);
    }
  }

#pragma unroll
  for (int r = 0; r < 4; ++r) {
    float s = lsum[r];
    s += __shfl_xor(s, 1);
    s += __shfl_xor(s, 2);
    s += __shfl_xor(s, 4);
    s += __shfl_xor(s, 8);
    lsum[r] = 1.f / s;
  }
#pragma unroll
  for (int r = 0; r < 4; ++r) {
    const int gq = blockIdx.x * 64 + w * 16 + quad * 4 + r;
    short* drow = ao16 + ((long)(bpar * kN + gq)) * kDim + blockIdx.y * kHd;
#pragma unroll
    for (int t = 0; t < 4; ++t)
      drow[t * 16 + k15] = (short)f2bf(accO[t][r] * lsum[r]);
  }
}

__global__ __launch_bounds__(256, 2) void r3_proj_kernel(
    const short* __restrict__ A16, const float* __restrict__ W,
    const float* __restrict__ bias, float* __restrict__ out) {
  __shared__ short As[128 * kP];
  __shared__ short Ws[128 * kP];
  const int tid  = threadIdx.x;
  const int w    = tid >> 6;
  const int lane = tid & 63;
  const int quad = lane >> 4;
  const int k15  = lane & 15;
  const int m0 = blockIdx.x * 128;
  const int n0 = blockIdx.y * 128;
  const int wm = (w >> 1) * 64;
  const int wn = (w & 1) * 64;

  f32x4 acc[4][4];
#pragma unroll
  for (int i = 0; i < 4; ++i)
#pragma unroll
    for (int j = 0; j < 4; ++j) acc[i][j] = (f32x4){0.f, 0.f, 0.f, 0.f};

  for (int kt = 0; kt < kDim; kt += 64) {
    __syncthreads();
#pragma unroll
    for (int p = 0; p < 4; ++p) {
      const int idx = p * 256 + tid;
      const int row = idx >> 3;
      const int c8  = (idx & 7) << 3;
      *(bf16x8*)&As[row * kP + c8] =
          *(const bf16x8*)&A16[(long)(m0 + row) * kDim + kt + c8];
    }
#pragma unroll
    for (int p = 0; p < 8; ++p) {
      const int idx = p * 256 + tid;
      const int row = idx >> 4;
      const int c4  = (idx & 15) << 2;
      float4 wv = *(const float4*)&W[(long)(n0 + row) * kDim + kt + c4];
      uint2 wp = {pack2bf(wv.x, wv.y), pack2bf(wv.z, wv.w)};
      *(uint2*)&Ws[row * kP + c4] = wp;
    }
    __syncthreads();
#pragma unroll
    for (int ks = 0; ks < 2; ++ks) {
      bf16x8 af[4], bf[4];
#pragma unroll
      for (int t = 0; t < 4; ++t) {
        af[t] = *(const bf16x8*)&As[(wm + t * 16 + k15) * kP + ks * 32 + quad * 8];
        bf[t] = *(const bf16x8*)&Ws[(wn + t * 16 + k15) * kP + ks * 32 + quad * 8];
      }
#pragma unroll
      for (int mt = 0; mt < 4; ++mt)
#pragma unroll
        for (int nt = 0; nt < 4; ++nt)
          acc[mt][nt] = __builtin_amdgcn_mfma_f32_16x16x32_bf16(
              af[mt], bf[nt], acc[mt][nt], 0, 0, 0);
    }
  }

#pragma unroll
  for (int nt = 0; nt < 4; ++nt) {
    const int d = n0 + wn + nt * 16 + k15;
    const float bb = bias[d];
#pragma unroll
    for (int mt = 0; mt < 4; ++mt) {
#pragma unroll
      for (int r = 0; r < 4; ++r) {
        const int m = m0 + wm + mt * 16 + quad * 4 + r;
        out[(long)m * kDim + d] = acc[mt][nt][r] + bb;
      }
    }
  }
}

// ---------------------------------------------------------------------------
extern "C" void kernel_launch(void* const* d_in, const int* in_sizes, int n_in,
                              void* d_out, int out_size, void* d_ws, size_t ws_size,
                              hipStream_t stream) {
  const float* x      = (const float*)d_in[0];
  const float* qkv_w  = (const float*)d_in[1];
  const float* proj_w = (const float*)d_in[2];
  const float* proj_b = (const float*)d_in[3];
  float* out = (float*)d_out;

  short* ws = (short*)d_ws;
  const size_t MiS = 1048576;

  if (ws_size >= 41943040ull) {
    // Path A (40 MiB): X16 aliased with ao.
    short* X16  = ws;              // [4096,1024]
    short* W16  = ws + 4 * MiS;    // [3072,1024]
    short* PW16 = ws + 7 * MiS;    // [1024,1024]
    short* q16  = ws + 8 * MiS;    // [2][16][2048][64]
    short* k16  = ws + 12 * MiS;   // [2][16][2048][64]
    short* vT16 = ws + 16 * MiS;   // [2][16][64][2048]
    short* ao16 = X16;

    cvt3_kernel<<<4096, 256, 0, stream>>>(x, X16, 2048, qkv_w, W16, 1536,
                                          proj_w, PW16);
    mm_qkv_kernel<<<dim3(32, 24), 256, 0, stream>>>(X16, W16, q16, k16, vT16);
    attn_kernel<<<512, 512, 0, stream>>>(q16, k16, vT16, ao16);
    mm_proj_kernel<<<dim3(32, 8), 256, 0, stream>>>(ao16, PW16, proj_b, out);
    return;
  }

  // Path C fallback (20 MiB, proven structure).
  {
    short* q16  = ws;
    short* k16  = ws + 2 * MiS;
    short* v16  = ws + 4 * MiS;
    short* ao16 = ws + 6 * MiS;
    for (int b = 0; b < kB; ++b) {
      r3_qkv_kernel<<<dim3(16, 24), 256, 0, stream>>>(
          x + (size_t)b * kN * kDim, qkv_w, q16, k16, v16);
      attn_v1_kernel<<<dim3(32, 16), 256, 0, stream>>>(q16, k16, v16, ao16, b);
    }
    r3_proj_kernel<<<dim3(32, 8), 256, 0, stream>>>(ao16, proj_w, proj_b, out);
  }
}

// Round 12
// 165.352 us; speedup vs baseline: 1.1664x; 1.1664x over previous
//
#include <hip/hip_runtime.h>
#include <cmath>

// MemoryEfficientAttention: x[2,2048,1024] -> qkv -> 16-head attn -> proj.
// Round 19 = Round 18 with the V-staging swizzle typo fixed: R11 failed
// because the "verbatim" attn revert had `& 15` instead of `& 7` in the V
// gl_lds16 swizzle (write-side walked out of its 64-short row; read side
// used the 3-bit swizzle -> mismatch, absmax 0.218). attn is now truly
// byte-equal to R8's proven v10 (45.6us). Lever under test: XCD-aware
// 2D-chunked swizzle on both GEMMs (bijective; qkv 8x12 panels/XCD ~5MB,
// proj 4x8 ~3MB -> staging hits L2 instead of L3/HBM).

namespace {
constexpr int kDim   = 1024;
constexpr int kHeads = 16;
constexpr int kHd    = 64;
constexpr int kB     = 2;
constexpr int kN     = 2048;
constexpr int kM     = kB * kN;
constexpr float kScale  = 0.125f;                       // 1/sqrt(64)
constexpr float kQScale = 0.125f * 1.44269504088896f;   // fold log2(e)
constexpr int kP = 72;              // padded LDS stride (qkv-T bounce / path C)
}  // namespace

typedef __attribute__((ext_vector_type(8))) short bf16x8;
typedef __attribute__((ext_vector_type(4))) float f32x4;

#if __has_builtin(__builtin_amdgcn_exp2f)
#define EXP2(x) __builtin_amdgcn_exp2f(x)
#else
#define EXP2(x) __expf((x) * 0.6931471805599453f)
#endif

__device__ inline unsigned short f2bf(float x) {
  union { float f; unsigned u; } un; un.f = x;
  unsigned r = un.u + 0x7fffu + ((un.u >> 16) & 1u);   // RNE
  return (unsigned short)(r >> 16);
}
__device__ inline unsigned pack2bf(float x, float y) {
  return (unsigned)f2bf(x) | ((unsigned)f2bf(y) << 16);
}
__device__ inline void gl_lds16(const short* g, short* l) {
  __builtin_amdgcn_global_load_lds(
      (const __attribute__((address_space(1))) unsigned*)g,
      (__attribute__((address_space(3))) unsigned*)l, 16, 0, 0);
}

// ---------------------------------------------------------------------------
// Merged fp32->bf16 convert: blocks [0,n0) -> a, [n0,n0+n1) -> b, rest -> c.
__global__ __launch_bounds__(256) void cvt3_kernel(
    const float* __restrict__ a, short* __restrict__ da, int n0,
    const float* __restrict__ b, short* __restrict__ db, int n1,
    const float* __restrict__ c, short* __restrict__ dc) {
  int blk = blockIdx.x;
  const float* src; short* dst;
  if (blk < n0) { src = a; dst = da; }
  else if (blk < n0 + n1) { src = b; dst = db; blk -= n0; }
  else { src = c; dst = dc; blk -= n0 + n1; }
  const int i = (blk * 256 + threadIdx.x) * 8;
  float4 u = *(const float4*)&src[i];
  float4 v = *(const float4*)&src[i + 4];
  bf16x8 o = {(short)f2bf(u.x), (short)f2bf(u.y), (short)f2bf(u.z), (short)f2bf(u.w),
              (short)f2bf(v.x), (short)f2bf(v.y), (short)f2bf(v.z), (short)f2bf(v.w)};
  *(bf16x8*)&dst[i] = o;
}

// ---------------------------------------------------------------------------
// QKV GEMM (path A): A16[4096,1024] @ W16[3072,1024]^T. 128x128 tile, BK=64,
// global_load_lds + XOR swizzle, 2-phase prefetch (dbuf LDS, stage(next)
// before compute(cur), one __syncthreads per K-tile). Flat 768-block grid
// with XCD 2D-chunk swizzle: xcd=bid&7 owns an 8(x) x 12(y) panel region
// (A 2MB + W 3MB ~ L2-resident). Epilogue: Q scaled by kQScale ->
// [b][h][n][dh]; K -> [b][h][n][dh]; V -> TRANSPOSED [b][h][dh][n].
__global__ __launch_bounds__(256, 2) void mm_qkv_kernel(
    const short* __restrict__ A16, const short* __restrict__ W16,
    short* __restrict__ q16, short* __restrict__ k16, short* __restrict__ vT16) {
  __shared__ short smem[2 * 2 * 128 * 64];   // 64 KiB: [buf][A|B][128][64]
  const int tid  = threadIdx.x;
  const int w    = tid >> 6;
  const int lane = tid & 63;
  const int quad = lane >> 4;
  const int k15  = lane & 15;

  // XCD 2D-chunk decode: consecutive bids round-robin XCDs, so bid&7 pins
  // the XCD; each XCD covers x in [xq*8,xq*8+8), y in [yh*12,yh*12+12).
  const int bid = blockIdx.x;          // 0..767
  const int xcd = bid & 7;
  const int idx = bid >> 3;            // 0..95
  const int bx  = (xcd & 3) * 8 + (idx & 7);    // 0..31
  const int by  = (xcd >> 2) * 12 + (idx >> 3); // 0..23

  const int m0   = bx * 128;
  const int seg  = by >> 3;
  const int nt0  = (by & 7) << 7;
  const int wrow0 = seg * 1024 + nt0;
  const int wm = (w >> 1) * 64;
  const int wn = (w & 1) * 64;
  const int lrow   = lane >> 3;
  const int lchunk = (lane & 7) ^ lrow;

  f32x4 acc[4][4];
#pragma unroll
  for (int i = 0; i < 4; ++i)
#pragma unroll
    for (int j = 0; j < 4; ++j) acc[i][j] = (f32x4){0.f, 0.f, 0.f, 0.f};

  auto stage = [&](int kt, int buf) {
    short* As = smem + buf * 16384;
    short* Bs = As + 8192;
    const int koff = kt * 64;
#pragma unroll
    for (int p = 0; p < 4; ++p) {
      const int r0 = p * 32 + w * 8;
      gl_lds16(&A16[(long)(m0 + r0 + lrow) * 1024 + koff + lchunk * 8], &As[r0 * 64]);
      gl_lds16(&W16[(long)(wrow0 + r0 + lrow) * 1024 + koff + lchunk * 8], &Bs[r0 * 64]);
    }
  };

  stage(0, 0);
  __syncthreads();
  for (int kt = 0; kt < 16; ++kt) {
    if (kt + 1 < 16) stage(kt + 1, (kt + 1) & 1);   // prefetch under compute
    const short* As = smem + (kt & 1) * 16384;
    const short* Bs = As + 8192;
#pragma unroll
    for (int ks = 0; ks < 2; ++ks) {
      bf16x8 af[4], bf[4];
#pragma unroll
      for (int t = 0; t < 4; ++t) {
        const int Ra = wm + t * 16 + k15;
        af[t] = *(const bf16x8*)&As[Ra * 64 + (((ks << 2) + quad) ^ (Ra & 7)) * 8];
        const int Rb = wn + t * 16 + k15;
        bf[t] = *(const bf16x8*)&Bs[Rb * 64 + (((ks << 2) + quad) ^ (Rb & 7)) * 8];
      }
#pragma unroll
      for (int mt = 0; mt < 4; ++mt)
#pragma unroll
        for (int nt = 0; nt < 4; ++nt)
          acc[mt][nt] = __builtin_amdgcn_mfma_f32_16x16x32_bf16(
              af[mt], bf[nt], acc[mt][nt], 0, 0, 0);
    }
    __syncthreads();
  }

  if (seg < 2) {
    short* dst = (seg == 0) ? q16 : k16;
    const float sc = (seg == 0) ? kQScale : 1.0f;
#pragma unroll
    for (int nt = 0; nt < 4; ++nt) {
      const int dl = nt0 + wn + nt * 16 + k15;
      const int h  = dl >> 6;
      const int dh = dl & 63;
#pragma unroll
      for (int mt = 0; mt < 4; ++mt) {
#pragma unroll
        for (int r = 0; r < 4; ++r) {
          const int ml = m0 + wm + mt * 16 + quad * 4 + r;
          const int b  = ml >> 11;
          const int n  = ml & 2047;
          dst[(((long)(b * kHeads + h) * kN) + n) * kHd + dh] =
              (short)f2bf(acc[mt][nt][r] * sc);
        }
      }
    }
  } else {
    __syncthreads();
    short* Tw = smem + w * 16 * kP;
#pragma unroll
    for (int nt = 0; nt < 4; ++nt) {
#pragma unroll
      for (int mt = 0; mt < 4; ++mt) {
        uint2 pk;
        pk.x = pack2bf(acc[mt][nt][0], acc[mt][nt][1]);
        pk.y = pack2bf(acc[mt][nt][2], acc[mt][nt][3]);
        *(uint2*)&Tw[k15 * kP + mt * 16 + quad * 4] = pk;
      }
#pragma unroll
      for (int i = 0; i < 2; ++i) {
        const int idx2  = i * 64 + lane;
        const int trow = idx2 >> 3;
        const int tch  = idx2 & 7;
        bf16x8 row = *(const bf16x8*)&Tw[trow * kP + tch * 8];
        const int vcol = nt0 + wn + nt * 16 + trow;
        const int h  = vcol >> 6;
        const int dh = vcol & 63;
        const int m  = m0 + wm + tch * 8;
        const int b  = m >> 11;
        const int n  = m & 2047;
        *(bf16x8*)&vT16[(((long)(b * kHeads + h) * kHd) + dh) * kN + n] = row;
      }
    }
  }
}

// ---------------------------------------------------------------------------
// proj GEMM: out = ao16[4096,1024] @ PW16[1024,1024]^T + bias (fp32 out).
// Same 2-phase prefetch structure as mm_qkv. Flat 256-block grid with XCD
// 2D-chunk swizzle: xcd owns x in [xcd*4,xcd*4+4), all y (A 1MB + B 2MB).
__global__ __launch_bounds__(256, 2) void mm_proj_kernel(
    const short* __restrict__ A16, const short* __restrict__ B16,
    const float* __restrict__ bias, float* __restrict__ out) {
  __shared__ short smem[2 * 2 * 128 * 64];   // 64 KiB: [buf][A|B][128][64]
  const int tid  = threadIdx.x;
  const int w    = tid >> 6;
  const int lane = tid & 63;
  const int quad = lane >> 4;
  const int k15  = lane & 15;

  const int bid = blockIdx.x;          // 0..255
  const int xcd = bid & 7;
  const int idx = bid >> 3;            // 0..31
  const int bx  = xcd * 4 + (idx & 3); // 0..31
  const int by  = idx >> 2;            // 0..7

  const int m0 = bx * 128;
  const int n0 = by * 128;
  const int wm = (w >> 1) * 64;
  const int wn = (w & 1) * 64;
  const int lrow   = lane >> 3;
  const int lchunk = (lane & 7) ^ lrow;

  f32x4 acc[4][4];
#pragma unroll
  for (int i = 0; i < 4; ++i)
#pragma unroll
    for (int j = 0; j < 4; ++j) acc[i][j] = (f32x4){0.f, 0.f, 0.f, 0.f};

  auto stage = [&](int kt, int buf) {
    short* As = smem + buf * 16384;
    short* Bs = As + 8192;
    const int koff = kt * 64;
#pragma unroll
    for (int p = 0; p < 4; ++p) {
      const int r0 = p * 32 + w * 8;
      gl_lds16(&A16[(long)(m0 + r0 + lrow) * 1024 + koff + lchunk * 8], &As[r0 * 64]);
      gl_lds16(&B16[(long)(n0 + r0 + lrow) * 1024 + koff + lchunk * 8], &Bs[r0 * 64]);
    }
  };

  stage(0, 0);
  __syncthreads();
  for (int kt = 0; kt < 16; ++kt) {
    if (kt + 1 < 16) stage(kt + 1, (kt + 1) & 1);   // prefetch under compute
    const short* As = smem + (kt & 1) * 16384;
    const short* Bs = As + 8192;
#pragma unroll
    for (int ks = 0; ks < 2; ++ks) {
      bf16x8 af[4], bf[4];
#pragma unroll
      for (int t = 0; t < 4; ++t) {
        const int Ra = wm + t * 16 + k15;
        af[t] = *(const bf16x8*)&As[Ra * 64 + (((ks << 2) + quad) ^ (Ra & 7)) * 8];
        const int Rb = wn + t * 16 + k15;
        bf[t] = *(const bf16x8*)&Bs[Rb * 64 + (((ks << 2) + quad) ^ (Rb & 7)) * 8];
      }
#pragma unroll
      for (int mt = 0; mt < 4; ++mt)
#pragma unroll
        for (int nt = 0; nt < 4; ++nt)
          acc[mt][nt] = __builtin_amdgcn_mfma_f32_16x16x32_bf16(
              af[mt], bf[nt], acc[mt][nt], 0, 0, 0);
    }
    __syncthreads();
  }

#pragma unroll
  for (int nt = 0; nt < 4; ++nt) {
    const int d = n0 + wn + nt * 16 + k15;
    const float bb = bias[d];
#pragma unroll
    for (int mt = 0; mt < 4; ++mt) {
#pragma unroll
      for (int r = 0; r < 4; ++r) {
        const int m = m0 + wm + mt * 16 + quad * 4 + r;
        out[(long)m * 1024 + d] = acc[mt][nt][r] + bb;
      }
    }
  }
}

// ---------------------------------------------------------------------------
// Flash attention v10 (R8, proven 45.6us): block = 512 threads = 8 waves =
// {2 key-groups} x {4 q-subwaves}; wave = 32 q-rows (2 qt), 1024 keys in
// 16 x 64-key double-buffered tiles; stage(next) under compute(cur), one
// __syncthreads per tile (raw s_barrier is NOT safe: ds_reads can slide
// between own vmcnt-drain and the barrier and read other waves' unstaged
// rows). Swapped QK^T (mfma(K,Q)); P->A-frag in-register via cvt_pk_bf16 +
// permlane swaps; linear partial (O,L) merged in-block.
// waves_per_eu(2,4): only combo measured to avoid allocator spill (R4).
__global__ __launch_bounds__(512)
__attribute__((amdgpu_waves_per_eu(2, 4)))
void attn_kernel(
    const short* __restrict__ q16, const short* __restrict__ k16,
    const short* __restrict__ vT16, short* __restrict__ ao16) {
  // 64 KiB: [0,32K) = K tiles [g][buf][64 key][64 dh], [32K,64K) = V tiles
  // [g][buf][64 dh][64 key]; both chunk-XOR swizzled. Reused for the merge.
  __shared__ __align__(16) short smem[8 * 4096];

  const int tid  = threadIdx.x;         // 0..511
  const int w    = tid >> 6;            // 0..7
  const int g    = w >> 2;              // key-group: 0 -> [0,1024), 1 -> [1024,2048)
  const int sw   = w & 3;               // q-subwave: rows [sw*32, sw*32+32)
  const int lane = tid & 63;
  const int quad = lane >> 4;
  const int k15  = lane & 15;
  const int lrow8 = lane >> 3;          // staging: 8 rows x 8 chunks per call
  const int lch8  = lane & 7;
  const long base = (long)(blockIdx.z * kHeads + blockIdx.y) * kN * kHd;

  // Q B-frags: 2 qt tiles (32 rows). Waves w and w+4 load the same rows.
  bf16x8 qf[2][2];
#pragma unroll
  for (int qt = 0; qt < 2; ++qt) {
    const long qr = base + (long)(blockIdx.x * 128 + sw * 32 + qt * 16 + k15) * kHd;
    qf[qt][0] = *(const bf16x8*)&q16[qr + quad * 8];
    qf[qt][1] = *(const bf16x8*)&q16[qr + 32 + quad * 8];
  }

  f32x4 accO[2][4];
#pragma unroll
  for (int qt = 0; qt < 2; ++qt)
#pragma unroll
    for (int d = 0; d < 4; ++d) accO[qt][d] = (f32x4){0.f, 0.f, 0.f, 0.f};
  float lacc[2] = {0.f, 0.f};

  const short* kg0 = k16 + base + (long)g * 1024 * kHd;
  const short* vg0 = vT16 + base + g * 1024;

  // Stage one 64-key tile for this wave's group into buffer `buf`.
  auto stage = [&](int kt, int buf) {
    const short* kg = kg0 + (long)kt * 64 * kHd;
    const short* vg = vg0 + kt * 64;
    short* Kb = &smem[(g * 2 + buf) * 4096];
    short* Vb = &smem[(4 + g * 2 + buf) * 4096];
#pragma unroll
    for (int c = 0; c < 2; ++c) {       // K: 64 rows x 128B, 4 waves/group
      const int r0 = sw * 16 + c * 8;
      gl_lds16(kg + (long)(r0 + lrow8) * kHd + (lch8 ^ ((r0 + lrow8) & 7)) * 8,
               &Kb[r0 * 64]);
    }
#pragma unroll
    for (int c = 0; c < 2; ++c) {       // V: 64 dh-rows x 128B
      const int r0 = sw * 16 + c * 8;
      gl_lds16(vg + (long)(r0 + lrow8) * kN + (lch8 ^ ((r0 + lrow8) & 7)) * 8,
               &Vb[r0 * 64]);
    }
  };

  // Compute one 64-key tile from buffer `buf`.
  auto compute = [&](int buf) {
    const short* Kc = &smem[(g * 2 + buf) * 4096];
    const short* Vc = &smem[(4 + g * 2 + buf) * 4096];

    // QK^T swapped: sc[qt][t] = S^T tile, col = q (k15), row = key (quad*4+r).
    f32x4 sc[2][4];
    __builtin_amdgcn_s_setprio(1);
#pragma unroll
    for (int t = 0; t < 4; ++t) {
      const int row = t * 16 + k15;
      bf16x8 kb0 = *(const bf16x8*)&Kc[row * 64 + ((quad)     ^ (row & 7)) * 8];
      bf16x8 kb1 = *(const bf16x8*)&Kc[row * 64 + ((4 + quad) ^ (row & 7)) * 8];
      f32x4 z0 = {0.f, 0.f, 0.f, 0.f};
      z0 = __builtin_amdgcn_mfma_f32_16x16x32_bf16(kb0, qf[0][0], z0, 0, 0, 0);
      z0 = __builtin_amdgcn_mfma_f32_16x16x32_bf16(kb1, qf[0][1], z0, 0, 0, 0);
      sc[0][t] = z0;
      f32x4 z1 = {0.f, 0.f, 0.f, 0.f};
      z1 = __builtin_amdgcn_mfma_f32_16x16x32_bf16(kb0, qf[1][0], z1, 0, 0, 0);
      z1 = __builtin_amdgcn_mfma_f32_16x16x32_bf16(kb1, qf[1][1], z1, 0, 0, 0);
      sc[1][t] = z1;
    }
    __builtin_amdgcn_s_setprio(0);

    // exp2 + RNE pack to bf16 pairs; lane-local row-sum accumulation.
    unsigned pk[2][4][2];
#pragma unroll
    for (int qt = 0; qt < 2; ++qt) {
      float ls = 0.f;
#pragma unroll
      for (int t = 0; t < 4; ++t) {
        const float p0 = EXP2(sc[qt][t][0]);
        const float p1 = EXP2(sc[qt][t][1]);
        const float p2 = EXP2(sc[qt][t][2]);
        const float p3 = EXP2(sc[qt][t][3]);
        ls += (p0 + p1) + (p2 + p3);
        asm("v_cvt_pk_bf16_f32 %0, %1, %2" : "=v"(pk[qt][t][0]) : "v"(p0), "v"(p1));
        asm("v_cvt_pk_bf16_f32 %0, %1, %2" : "=v"(pk[qt][t][1]) : "v"(p2), "v"(p3));
      }
      lacc[qt] += ls;
    }

#pragma unroll
    for (int kc = 0; kc < 2; ++kc) {
      // Redistribute so lane (quad,q) holds keys kc*32 + quad*8 + {0..7}.
      union { unsigned u[4]; bf16x8 v; } pf[2];
#pragma unroll
      for (int qt = 0; qt < 2; ++qt) {
        unsigned a = pk[qt][2 * kc][0],     b = pk[qt][2 * kc][1];
        unsigned c = pk[qt][2 * kc + 1][0], d4 = pk[qt][2 * kc + 1][1];
        asm("v_permlane32_swap_b32 %0, %1" : "+v"(a), "+v"(c));
        asm("v_permlane16_swap_b32 %0, %1" : "+v"(a), "+v"(c));
        asm("v_permlane32_swap_b32 %0, %1" : "+v"(b), "+v"(d4));
        asm("v_permlane16_swap_b32 %0, %1" : "+v"(b), "+v"(d4));
        pf[qt].u[0] = a; pf[qt].u[1] = b; pf[qt].u[2] = c; pf[qt].u[3] = d4;
      }
      __builtin_amdgcn_s_setprio(1);
#pragma unroll
      for (int d = 0; d < 4; ++d) {
        const int vrow = d * 16 + k15;
        const int ch = (kc * 4 + quad) ^ (vrow & 7);
        bf16x8 vb = *(const bf16x8*)&Vc[vrow * 64 + ch * 8];
        accO[0][d] = __builtin_amdgcn_mfma_f32_16x16x32_bf16(pf[0].v, vb, accO[0][d], 0, 0, 0);
        accO[1][d] = __builtin_amdgcn_mfma_f32_16x16x32_bf16(pf[1].v, vb, accO[1][d], 0, 0, 0);
      }
      __builtin_amdgcn_s_setprio(0);
    }
  };

  stage(0, 0);
  __syncthreads();
  for (int kt = 0; kt < 16; ++kt) {
    if (kt + 1 < 16) stage(kt + 1, (kt + 1) & 1);   // prefetch under compute
    compute(kt & 1);
    __syncthreads();
  }

  // Per-wave partial row sums: lane (quad,q) holds 1/4 of its group's L[q].
  float s[2];
#pragma unroll
  for (int qt = 0; qt < 2; ++qt) {
    float v = lacc[qt];
    v += __shfl_xor(v, 16);
    v += __shfl_xor(v, 32);
    s[qt] = v;                      // L_partial[q = k15], replicated over quads
  }

  // In-block merge: group-1 waves publish (O, L) partials; group-0 adds,
  // normalizes, stores. Slot: 8 KiB accO + 512 B L per q-subwave.
  // The loop-final __syncthreads already fenced the last compute's reads.
  {
    char* slot = (char*)smem + sw * 8704;
    f32x4* so = (f32x4*)slot;
    float* sl = (float*)(slot + 8192);
    if (w >= 4) {
#pragma unroll
      for (int qt = 0; qt < 2; ++qt) {
#pragma unroll
        for (int d = 0; d < 4; ++d) so[(qt * 4 + d) * 64 + lane] = accO[qt][d];
        sl[qt * 64 + lane] = s[qt];
      }
    }
    __syncthreads();
    if (w < 4) {
#pragma unroll
      for (int qt = 0; qt < 2; ++qt) {
        f32x4 am[4];
#pragma unroll
        for (int d = 0; d < 4; ++d)
          am[d] = accO[qt][d] + so[(qt * 4 + d) * 64 + lane];
        const float Lsum = s[qt] + sl[qt * 64 + lane];   // L[q=k15]
#pragma unroll
        for (int r = 0; r < 4; ++r) {
          const float Ls = __shfl(Lsum, quad * 4 + r);   // lanes 0..15 hold q
          const float in = 1.f / Ls;
          const int gq = blockIdx.x * 128 + sw * 32 + qt * 16 + quad * 4 + r;
          short* drow = ao16 + ((long)(blockIdx.z * kN + gq)) * kDim + blockIdx.y * kHd;
#pragma unroll
          for (int d = 0; d < 4; ++d)
            drow[d * 16 + k15] = (short)f2bf(am[d][r] * in);
        }
      }
    }
  }
}

// ---------------------------------------------------------------------------
// Path C fallback (proven r3-style, 20 MiB): fp32-input VGPR-staged kernels.
__global__ __launch_bounds__(256, 2) void r3_qkv_kernel(
    const float* __restrict__ X, const float* __restrict__ W,
    short* __restrict__ q16, short* __restrict__ k16, short* __restrict__ v16) {
  __shared__ short As[128 * kP];
  __shared__ short Ws[128 * kP];
  const int tid  = threadIdx.x;
  const int w    = tid >> 6;
  const int lane = tid & 63;
  const int quad = lane >> 4;
  const int k15  = lane & 15;
  const int m0 = blockIdx.x * 128;
  const int n0 = blockIdx.y * 128;
  const int wm = (w >> 1) * 64;
  const int wn = (w & 1) * 64;

  f32x4 acc[4][4];
#pragma unroll
  for (int i = 0; i < 4; ++i)
#pragma unroll
    for (int j = 0; j < 4; ++j) acc[i][j] = (f32x4){0.f, 0.f, 0.f, 0.f};

  for (int kt = 0; kt < kDim; kt += 64) {
    __syncthreads();
#pragma unroll
    for (int p = 0; p < 8; ++p) {
      const int idx = p * 256 + tid;
      const int row = idx >> 4;
      const int c4  = (idx & 15) << 2;
      float4 av = *(const float4*)&X[(long)(m0 + row) * kDim + kt + c4];
      uint2 ap = {pack2bf(av.x, av.y), pack2bf(av.z, av.w)};
      *(uint2*)&As[row * kP + c4] = ap;
      float4 wv = *(const float4*)&W[(long)(n0 + row) * kDim + kt + c4];
      uint2 wp = {pack2bf(wv.x, wv.y), pack2bf(wv.z, wv.w)};
      *(uint2*)&Ws[row * kP + c4] = wp;
    }
    __syncthreads();
#pragma unroll
    for (int ks = 0; ks < 2; ++ks) {
      bf16x8 af[4], bf[4];
#pragma unroll
      for (int t = 0; t < 4; ++t) {
        af[t] = *(const bf16x8*)&As[(wm + t * 16 + k15) * kP + ks * 32 + quad * 8];
        bf[t] = *(const bf16x8*)&Ws[(wn + t * 16 + k15) * kP + ks * 32 + quad * 8];
      }
#pragma unroll
      for (int mt = 0; mt < 4; ++mt)
#pragma unroll
        for (int nt = 0; nt < 4; ++nt)
          acc[mt][nt] = __builtin_amdgcn_mfma_f32_16x16x32_bf16(
              af[mt], bf[nt], acc[mt][nt], 0, 0, 0);
    }
  }

  const int t_sel = n0 >> 10;
  short* dst = (t_sel == 0) ? q16 : (t_sel == 1) ? k16 : v16;
  const float scl = (t_sel == 0) ? kScale : 1.0f;
#pragma unroll
  for (int nt = 0; nt < 4; ++nt) {
    const int d  = n0 + wn + nt * 16 + k15;
    const int h  = (d >> 6) & 15;
    const int dh = d & 63;
#pragma unroll
    for (int mt = 0; mt < 4; ++mt) {
#pragma unroll
      for (int r = 0; r < 4; ++r) {
        const int m = m0 + wm + mt * 16 + quad * 4 + r;
        dst[((long)h * kN + m) * kHd + dh] = (short)f2bf(acc[mt][nt][r] * scl);
      }
    }
  }
}

__global__ __launch_bounds__(256, 4) void attn_v1_kernel(
    const short* __restrict__ q16, const short* __restrict__ k16,
    const short* __restrict__ v16, short* __restrict__ ao16, int bpar) {
  __shared__ short Ks[64 * kP];
  __shared__ short Vs[64 * kP];
  __shared__ short Ps[4 * 16 * kP];
  const int tid  = threadIdx.x;
  const int w    = tid >> 6;
  const int lane = tid & 63;
  const int quad = lane >> 4;
  const int k15  = lane & 15;
  const long base = (long)blockIdx.y * kN * kHd;
  const int qrow = blockIdx.x * 64 + w * 16 + k15;
  const short* qp = q16 + base + (long)qrow * kHd + quad * 8;
  bf16x8 qf0 = *(const bf16x8*)(qp);
  bf16x8 qf1 = *(const bf16x8*)(qp + 32);

  f32x4 accO[4] = {{0.f,0.f,0.f,0.f},{0.f,0.f,0.f,0.f},
                   {0.f,0.f,0.f,0.f},{0.f,0.f,0.f,0.f}};
  float lsum[4] = {0.f, 0.f, 0.f, 0.f};

  for (int kt = 0; kt < kN / 64; ++kt) {
    __syncthreads();
    {
      const short* kg = k16 + base + (long)kt * 64 * kHd;
      const short* vg = v16 + base + (long)kt * 64 * kHd;
#pragma unroll
      for (int p = 0; p < 2; ++p) {
        const int idx = p * 256 + tid;
        const int key = idx >> 3;
        const int c8  = (idx & 7) << 3;
        *(bf16x8*)&Ks[key * kP + c8] = *(const bf16x8*)&kg[key * kHd + c8];
        bf16x8 vv = *(const bf16x8*)&vg[key * kHd + c8];
#pragma unroll
        for (int j = 0; j < 8; ++j) Vs[(c8 + j) * kP + key] = vv[j];
      }
    }
    __syncthreads();

    f32x4 sc[4];
#pragma unroll
    for (int t = 0; t < 4; ++t) {
      bf16x8 kb0 = *(const bf16x8*)&Ks[(t * 16 + k15) * kP + quad * 8];
      bf16x8 kb1 = *(const bf16x8*)&Ks[(t * 16 + k15) * kP + 32 + quad * 8];
      f32x4 z = {0.f, 0.f, 0.f, 0.f};
      z = __builtin_amdgcn_mfma_f32_16x16x32_bf16(qf0, kb0, z, 0, 0, 0);
      z = __builtin_amdgcn_mfma_f32_16x16x32_bf16(qf1, kb1, z, 0, 0, 0);
      sc[t] = z;
    }
    short* pw = &Ps[w * (16 * kP)];
#pragma unroll
    for (int t = 0; t < 4; ++t) {
#pragma unroll
      for (int r = 0; r < 4; ++r) {
        const float p = __expf(sc[t][r]);
        lsum[r] += p;
        pw[(quad * 4 + r) * kP + t * 16 + k15] = (short)f2bf(p);
      }
    }
    bf16x8 pf0 = *(const bf16x8*)&pw[k15 * kP + quad * 8];
    bf16x8 pf1 = *(const bf16x8*)&pw[k15 * kP + 32 + quad * 8];
#pragma unroll
    for (int t = 0; t < 4; ++t) {
      bf16x8 vb0 = *(const bf16x8*)&Vs[(t * 16 + k15) * kP + quad * 8];
      bf16x8 vb1 = *(const bf16x8*)&Vs[(t * 16 + k15) * kP + 32 + quad * 8];
      accO[t] = __builtin_amdgcn_mfma_f32_16x16x32_bf16(pf0, vb0, accO[t], 0, 0, 0);
      accO[t] = __builtin_amdgcn_mfma_f32_16x16x32_bf16(pf1, vb1, accO[t], 0, 0, 0);
    }
  }

#pragma unroll
  for (int r = 0; r < 4; ++r) {
    float s = lsum[r];
    s += __shfl_xor(s, 1);
    s += __shfl_xor(s, 2);
    s += __shfl_xor(s, 4);
    s += __shfl_xor(s, 8);
    lsum[r] = 1.f / s;
  }
#pragma unroll
  for (int r = 0; r < 4; ++r) {
    const int gq = blockIdx.x * 64 + w * 16 + quad * 4 + r;
    short* drow = ao16 + ((long)(bpar * kN + gq)) * kDim + blockIdx.y * kHd;
#pragma unroll
    for (int t = 0; t < 4; ++t)
      drow[t * 16 + k15] = (short)f2bf(accO[t][r] * lsum[r]);
  }
}

__global__ __launch_bounds__(256, 2) void r3_proj_kernel(
    const short* __restrict__ A16, const float* __restrict__ W,
    const float* __restrict__ bias, float* __restrict__ out) {
  __shared__ short As[128 * kP];
  __shared__ short Ws[128 * kP];
  const int tid  = threadIdx.x;
  const int w    = tid >> 6;
  const int lane = tid & 63;
  const int quad = lane >> 4;
  const int k15  = lane & 15;
  const int m0 = blockIdx.x * 128;
  const int n0 = blockIdx.y * 128;
  const int wm = (w >> 1) * 64;
  const int wn = (w & 1) * 64;

  f32x4 acc[4][4];
#pragma unroll
  for (int i = 0; i < 4; ++i)
#pragma unroll
    for (int j = 0; j < 4; ++j) acc[i][j] = (f32x4){0.f, 0.f, 0.f, 0.f};

  for (int kt = 0; kt < kDim; kt += 64) {
    __syncthreads();
#pragma unroll
    for (int p = 0; p < 4; ++p) {
      const int idx = p * 256 + tid;
      const int row = idx >> 3;
      const int c8  = (idx & 7) << 3;
      *(bf16x8*)&As[row * kP + c8] =
          *(const bf16x8*)&A16[(long)(m0 + row) * kDim + kt + c8];
    }
#pragma unroll
    for (int p = 0; p < 8; ++p) {
      const int idx = p * 256 + tid;
      const int row = idx >> 4;
      const int c4  = (idx & 15) << 2;
      float4 wv = *(const float4*)&W[(long)(n0 + row) * kDim + kt + c4];
      uint2 wp = {pack2bf(wv.x, wv.y), pack2bf(wv.z, wv.w)};
      *(uint2*)&Ws[row * kP + c4] = wp;
    }
    __syncthreads();
#pragma unroll
    for (int ks = 0; ks < 2; ++ks) {
      bf16x8 af[4], bf[4];
#pragma unroll
      for (int t = 0; t < 4; ++t) {
        af[t] = *(const bf16x8*)&As[(wm + t * 16 + k15) * kP + ks * 32 + quad * 8];
        bf[t] = *(const bf16x8*)&Ws[(wn + t * 16 + k15) * kP + ks * 32 + quad * 8];
      }
#pragma unroll
      for (int mt = 0; mt < 4; ++mt)
#pragma unroll
        for (int nt = 0; nt < 4; ++nt)
          acc[mt][nt] = __builtin_amdgcn_mfma_f32_16x16x32_bf16(
              af[mt], bf[nt], acc[mt][nt], 0, 0, 0);
    }
  }

#pragma unroll
  for (int nt = 0; nt < 4; ++nt) {
    const int d = n0 + wn + nt * 16 + k15;
    const float bb = bias[d];
#pragma unroll
    for (int mt = 0; mt < 4; ++mt) {
#pragma unroll
      for (int r = 0; r < 4; ++r) {
        const int m = m0 + wm + mt * 16 + quad * 4 + r;
        out[(long)m * kDim + d] = acc[mt][nt][r] + bb;
      }
    }
  }
}

// ---------------------------------------------------------------------------
extern "C" void kernel_launch(void* const* d_in, const int* in_sizes, int n_in,
                              void* d_out, int out_size, void* d_ws, size_t ws_size,
                              hipStream_t stream) {
  const float* x      = (const float*)d_in[0];
  const float* qkv_w  = (const float*)d_in[1];
  const float* proj_w = (const float*)d_in[2];
  const float* proj_b = (const float*)d_in[3];
  float* out = (float*)d_out;

  short* ws = (short*)d_ws;
  const size_t MiS = 1048576;

  if (ws_size >= 41943040ull) {
    // Path A (40 MiB): X16 aliased with ao.
    short* X16  = ws;              // [4096,1024]
    short* W16  = ws + 4 * MiS;    // [3072,1024]
    short* PW16 = ws + 7 * MiS;    // [1024,1024]
    short* q16  = ws + 8 * MiS;    // [2][16][2048][64]
    short* k16  = ws + 12 * MiS;   // [2][16][2048][64]
    short* vT16 = ws + 16 * MiS;   // [2][16][64][2048]
    short* ao16 = X16;

    cvt3_kernel<<<4096, 256, 0, stream>>>(x, X16, 2048, qkv_w, W16, 1536,
                                          proj_w, PW16);
    mm_qkv_kernel<<<768, 256, 0, stream>>>(X16, W16, q16, k16, vT16);
    attn_kernel<<<dim3(16, 16, 2), 512, 0, stream>>>(q16, k16, vT16, ao16);
    mm_proj_kernel<<<256, 256, 0, stream>>>(ao16, PW16, proj_b, out);
    return;
  }

  // Path C fallback (20 MiB, proven structure).
  {
    short* q16  = ws;
    short* k16  = ws + 2 * MiS;
    short* v16  = ws + 4 * MiS;
    short* ao16 = ws + 6 * MiS;
    for (int b = 0; b < kB; ++b) {
      r3_qkv_kernel<<<dim3(16, 24), 256, 0, stream>>>(
          x + (size_t)b * kN * kDim, qkv_w, q16, k16, v16);
      attn_v1_kernel<<<dim3(32, 16), 256, 0, stream>>>(q16, k16, v16, ao16, b);
    }
    r3_proj_kernel<<<dim3(32, 8), 256, 0, stream>>>(ao16, proj_w, proj_b, out);
  }
}

// Round 13
// 165.243 us; speedup vs baseline: 1.1672x; 1.0007x over previous
//
#include <hip/hip_runtime.h>
#include <cmath>

// MemoryEfficientAttention: x[2,2048,1024] -> qkv -> 16-head attn -> proj.
// Round 20: zero-tail GEMM occupancy tuning (attn byte-equal to R12 ~46us).
// mm_qkv: single-buffer 32KB + launch_bounds(256,3) -> 3 blocks/CU, 768
// blocks = exactly 3x256 -> NO dispatch tail (R12's 64KB dbuf capped at
// 2/CU -> 1.5 dispatch waves, second half-empty; dbuf was measured ~neutral
// for GEMMs). mm_proj: 64x128 dbuf tile (48KB), flat 512 grid + XCD swizzle
// -> 2/CU, zero tail, 2x parallelism. XCD 2D-chunk swizzles kept (R12: -3.5us).

namespace {
constexpr int kDim   = 1024;
constexpr int kHeads = 16;
constexpr int kHd    = 64;
constexpr int kB     = 2;
constexpr int kN     = 2048;
constexpr int kM     = kB * kN;
constexpr float kScale  = 0.125f;                       // 1/sqrt(64)
constexpr float kQScale = 0.125f * 1.44269504088896f;   // fold log2(e)
constexpr int kP = 72;              // padded LDS stride (qkv-T bounce / path C)
}  // namespace

typedef __attribute__((ext_vector_type(8))) short bf16x8;
typedef __attribute__((ext_vector_type(4))) float f32x4;

#if __has_builtin(__builtin_amdgcn_exp2f)
#define EXP2(x) __builtin_amdgcn_exp2f(x)
#else
#define EXP2(x) __expf((x) * 0.6931471805599453f)
#endif

__device__ inline unsigned short f2bf(float x) {
  union { float f; unsigned u; } un; un.f = x;
  unsigned r = un.u + 0x7fffu + ((un.u >> 16) & 1u);   // RNE
  return (unsigned short)(r >> 16);
}
__device__ inline unsigned pack2bf(float x, float y) {
  return (unsigned)f2bf(x) | ((unsigned)f2bf(y) << 16);
}
__device__ inline void gl_lds16(const short* g, short* l) {
  __builtin_amdgcn_global_load_lds(
      (const __attribute__((address_space(1))) unsigned*)g,
      (__attribute__((address_space(3))) unsigned*)l, 16, 0, 0);
}

// ---------------------------------------------------------------------------
// Merged fp32->bf16 convert: blocks [0,n0) -> a, [n0,n0+n1) -> b, rest -> c.
__global__ __launch_bounds__(256) void cvt3_kernel(
    const float* __restrict__ a, short* __restrict__ da, int n0,
    const float* __restrict__ b, short* __restrict__ db, int n1,
    const float* __restrict__ c, short* __restrict__ dc) {
  int blk = blockIdx.x;
  const float* src; short* dst;
  if (blk < n0) { src = a; dst = da; }
  else if (blk < n0 + n1) { src = b; dst = db; blk -= n0; }
  else { src = c; dst = dc; blk -= n0 + n1; }
  const int i = (blk * 256 + threadIdx.x) * 8;
  float4 u = *(const float4*)&src[i];
  float4 v = *(const float4*)&src[i + 4];
  bf16x8 o = {(short)f2bf(u.x), (short)f2bf(u.y), (short)f2bf(u.z), (short)f2bf(u.w),
              (short)f2bf(v.x), (short)f2bf(v.y), (short)f2bf(v.z), (short)f2bf(v.w)};
  *(bf16x8*)&dst[i] = o;
}

// ---------------------------------------------------------------------------
// QKV GEMM (path A): A16[4096,1024] @ W16[3072,1024]^T. 128x128 tile, BK=64,
// global_load_lds + XOR swizzle, SINGLE-buffer 32KB LDS (stage -> sync ->
// compute -> sync), launch_bounds(256,3) -> 3 blocks/CU, 768 blocks = zero
// dispatch tail. Flat 768-block grid with XCD 2D-chunk swizzle: xcd=bid&7
// owns an 8(x) x 12(y) panel region (A 2MB + W 3MB ~ L2-resident).
// Epilogue: Q*kQScale -> [b][h][n][dh]; K -> [b][h][n][dh]; V -> [b][h][dh][n].
__global__ __launch_bounds__(256, 3) void mm_qkv_kernel(
    const short* __restrict__ A16, const short* __restrict__ W16,
    short* __restrict__ q16, short* __restrict__ k16, short* __restrict__ vT16) {
  __shared__ short smem[2 * 128 * 64];   // 32 KiB: [A|B][128][64]
  short* As = smem;
  short* Bs = smem + 128 * 64;
  const int tid  = threadIdx.x;
  const int w    = tid >> 6;
  const int lane = tid & 63;
  const int quad = lane >> 4;
  const int k15  = lane & 15;

  // XCD 2D-chunk decode: consecutive bids round-robin XCDs, so bid&7 pins
  // the XCD; each XCD covers x in [xq*8,xq*8+8), y in [yh*12,yh*12+12).
  const int bid = blockIdx.x;          // 0..767
  const int xcd = bid & 7;
  const int idx = bid >> 3;            // 0..95
  const int bx  = (xcd & 3) * 8 + (idx & 7);    // 0..31
  const int by  = (xcd >> 2) * 12 + (idx >> 3); // 0..23

  const int m0   = bx * 128;
  const int seg  = by >> 3;
  const int nt0  = (by & 7) << 7;
  const int wrow0 = seg * 1024 + nt0;
  const int wm = (w >> 1) * 64;
  const int wn = (w & 1) * 64;
  const int lrow   = lane >> 3;
  const int lchunk = (lane & 7) ^ lrow;

  f32x4 acc[4][4];
#pragma unroll
  for (int i = 0; i < 4; ++i)
#pragma unroll
    for (int j = 0; j < 4; ++j) acc[i][j] = (f32x4){0.f, 0.f, 0.f, 0.f};

  for (int kt = 0; kt < 1024; kt += 64) {
    __syncthreads();
#pragma unroll
    for (int p = 0; p < 4; ++p) {
      const int r0 = p * 32 + w * 8;
      gl_lds16(&A16[(long)(m0 + r0 + lrow) * 1024 + kt + lchunk * 8], &As[r0 * 64]);
      gl_lds16(&W16[(long)(wrow0 + r0 + lrow) * 1024 + kt + lchunk * 8], &Bs[r0 * 64]);
    }
    __syncthreads();
#pragma unroll
    for (int ks = 0; ks < 2; ++ks) {
      bf16x8 af[4], bf[4];
#pragma unroll
      for (int t = 0; t < 4; ++t) {
        const int Ra = wm + t * 16 + k15;
        af[t] = *(const bf16x8*)&As[Ra * 64 + (((ks << 2) + quad) ^ (Ra & 7)) * 8];
        const int Rb = wn + t * 16 + k15;
        bf[t] = *(const bf16x8*)&Bs[Rb * 64 + (((ks << 2) + quad) ^ (Rb & 7)) * 8];
      }
#pragma unroll
      for (int mt = 0; mt < 4; ++mt)
#pragma unroll
        for (int nt = 0; nt < 4; ++nt)
          acc[mt][nt] = __builtin_amdgcn_mfma_f32_16x16x32_bf16(
              af[mt], bf[nt], acc[mt][nt], 0, 0, 0);
    }
  }

  if (seg < 2) {
    short* dst = (seg == 0) ? q16 : k16;
    const float sc = (seg == 0) ? kQScale : 1.0f;
#pragma unroll
    for (int nt = 0; nt < 4; ++nt) {
      const int dl = nt0 + wn + nt * 16 + k15;
      const int h  = dl >> 6;
      const int dh = dl & 63;
#pragma unroll
      for (int mt = 0; mt < 4; ++mt) {
#pragma unroll
        for (int r = 0; r < 4; ++r) {
          const int ml = m0 + wm + mt * 16 + quad * 4 + r;
          const int b  = ml >> 11;
          const int n  = ml & 2047;
          dst[(((long)(b * kHeads + h) * kN) + n) * kHd + dh] =
              (short)f2bf(acc[mt][nt][r] * sc);
        }
      }
    }
  } else {
    __syncthreads();
    short* Tw = smem + w * 16 * kP;
#pragma unroll
    for (int nt = 0; nt < 4; ++nt) {
#pragma unroll
      for (int mt = 0; mt < 4; ++mt) {
        uint2 pk;
        pk.x = pack2bf(acc[mt][nt][0], acc[mt][nt][1]);
        pk.y = pack2bf(acc[mt][nt][2], acc[mt][nt][3]);
        *(uint2*)&Tw[k15 * kP + mt * 16 + quad * 4] = pk;
      }
#pragma unroll
      for (int i = 0; i < 2; ++i) {
        const int idx2  = i * 64 + lane;
        const int trow = idx2 >> 3;
        const int tch  = idx2 & 7;
        bf16x8 row = *(const bf16x8*)&Tw[trow * kP + tch * 8];
        const int vcol = nt0 + wn + nt * 16 + trow;
        const int h  = vcol >> 6;
        const int dh = vcol & 63;
        const int m  = m0 + wm + tch * 8;
        const int b  = m >> 11;
        const int n  = m & 2047;
        *(bf16x8*)&vT16[(((long)(b * kHeads + h) * kHd) + dh) * kN + n] = row;
      }
    }
  }
}

// ---------------------------------------------------------------------------
// proj GEMM: out = ao16[4096,1024] @ PW16[1024,1024]^T + bias (fp32 out).
// 64x128 tile, dbuf 48KB, 2-phase prefetch. Flat 512-block grid (zero tail,
// 2 blocks/CU) with XCD chunk swizzle: xcd owns bx in [xcd*8,xcd*8+8), all
// by (A 1MB + B 2MB ~ L2-resident).
__global__ __launch_bounds__(256, 2) void mm_proj_kernel(
    const short* __restrict__ A16, const short* __restrict__ B16,
    const float* __restrict__ bias, float* __restrict__ out) {
  __shared__ short smem[2 * (64 + 128) * 64];   // 48 KiB: [buf][A(64)|B(128)][64]
  const int tid  = threadIdx.x;
  const int w    = tid >> 6;
  const int lane = tid & 63;
  const int quad = lane >> 4;
  const int k15  = lane & 15;

  const int bid = blockIdx.x;          // 0..511
  const int xcd = bid & 7;
  const int idx = bid >> 3;            // 0..63
  const int bx  = xcd * 8 + (idx & 7); // 0..63 (m-tiles of 64)
  const int by  = idx >> 3;            // 0..7

  const int m0 = bx * 64;
  const int n0 = by * 128;
  const int wm = (w >> 1) * 32;        // {0,32}
  const int wn = (w & 1) * 64;         // {0,64}
  const int lrow   = lane >> 3;
  const int lchunk = (lane & 7) ^ lrow;

  f32x4 acc[2][4];
#pragma unroll
  for (int i = 0; i < 2; ++i)
#pragma unroll
    for (int j = 0; j < 4; ++j) acc[i][j] = (f32x4){0.f, 0.f, 0.f, 0.f};

  auto stage = [&](int kt, int buf) {
    short* As = smem + buf * 12288;
    short* Bs = As + 4096;
    const int koff = kt * 64;
#pragma unroll
    for (int c = 0; c < 2; ++c) {   // A: 64 rows, 8 calls, 2/wave
      const int r0 = w * 16 + c * 8;
      gl_lds16(&A16[(long)(m0 + r0 + lrow) * 1024 + koff + lchunk * 8], &As[r0 * 64]);
    }
#pragma unroll
    for (int c = 0; c < 4; ++c) {   // B: 128 rows, 16 calls, 4/wave
      const int r0 = w * 32 + c * 8;
      gl_lds16(&B16[(long)(n0 + r0 + lrow) * 1024 + koff + lchunk * 8], &Bs[r0 * 64]);
    }
  };

  stage(0, 0);
  __syncthreads();
  for (int kt = 0; kt < 16; ++kt) {
    if (kt + 1 < 16) stage(kt + 1, (kt + 1) & 1);   // prefetch under compute
    const short* As = smem + (kt & 1) * 12288;
    const short* Bs = As + 4096;
#pragma unroll
    for (int ks = 0; ks < 2; ++ks) {
      bf16x8 af[2], bf[4];
#pragma unroll
      for (int t = 0; t < 2; ++t) {
        const int Ra = wm + t * 16 + k15;
        af[t] = *(const bf16x8*)&As[Ra * 64 + (((ks << 2) + quad) ^ (Ra & 7)) * 8];
      }
#pragma unroll
      for (int t = 0; t < 4; ++t) {
        const int Rb = wn + t * 16 + k15;
        bf[t] = *(const bf16x8*)&Bs[Rb * 64 + (((ks << 2) + quad) ^ (Rb & 7)) * 8];
      }
#pragma unroll
      for (int mt = 0; mt < 2; ++mt)
#pragma unroll
        for (int nt = 0; nt < 4; ++nt)
          acc[mt][nt] = __builtin_amdgcn_mfma_f32_16x16x32_bf16(
              af[mt], bf[nt], acc[mt][nt], 0, 0, 0);
    }
    __syncthreads();
  }

#pragma unroll
  for (int nt = 0; nt < 4; ++nt) {
    const int d = n0 + wn + nt * 16 + k15;
    const float bb = bias[d];
#pragma unroll
    for (int mt = 0; mt < 2; ++mt) {
#pragma unroll
      for (int r = 0; r < 4; ++r) {
        const int m = m0 + wm + mt * 16 + quad * 4 + r;
        out[(long)m * 1024 + d] = acc[mt][nt][r] + bb;
      }
    }
  }
}

// ---------------------------------------------------------------------------
// Flash attention v10 (R8/R12, proven ~46us): block = 512 threads = 8 waves =
// {2 key-groups} x {4 q-subwaves}; wave = 32 q-rows (2 qt), 1024 keys in
// 16 x 64-key double-buffered tiles; stage(next) under compute(cur), one
// __syncthreads per tile (raw s_barrier is NOT safe: ds_reads can slide
// between own vmcnt-drain and the barrier and read other waves' unstaged
// rows). Swapped QK^T (mfma(K,Q)); P->A-frag in-register via cvt_pk_bf16 +
// permlane swaps; linear partial (O,L) merged in-block.
// waves_per_eu(2,4): only combo measured to avoid allocator spill (R4).
__global__ __launch_bounds__(512)
__attribute__((amdgpu_waves_per_eu(2, 4)))
void attn_kernel(
    const short* __restrict__ q16, const short* __restrict__ k16,
    const short* __restrict__ vT16, short* __restrict__ ao16) {
  // 64 KiB: [0,32K) = K tiles [g][buf][64 key][64 dh], [32K,64K) = V tiles
  // [g][buf][64 dh][64 key]; both chunk-XOR swizzled. Reused for the merge.
  __shared__ __align__(16) short smem[8 * 4096];

  const int tid  = threadIdx.x;         // 0..511
  const int w    = tid >> 6;            // 0..7
  const int g    = w >> 2;              // key-group: 0 -> [0,1024), 1 -> [1024,2048)
  const int sw   = w & 3;               // q-subwave: rows [sw*32, sw*32+32)
  const int lane = tid & 63;
  const int quad = lane >> 4;
  const int k15  = lane & 15;
  const int lrow8 = lane >> 3;          // staging: 8 rows x 8 chunks per call
  const int lch8  = lane & 7;
  const long base = (long)(blockIdx.z * kHeads + blockIdx.y) * kN * kHd;

  // Q B-frags: 2 qt tiles (32 rows). Waves w and w+4 load the same rows.
  bf16x8 qf[2][2];
#pragma unroll
  for (int qt = 0; qt < 2; ++qt) {
    const long qr = base + (long)(blockIdx.x * 128 + sw * 32 + qt * 16 + k15) * kHd;
    qf[qt][0] = *(const bf16x8*)&q16[qr + quad * 8];
    qf[qt][1] = *(const bf16x8*)&q16[qr + 32 + quad * 8];
  }

  f32x4 accO[2][4];
#pragma unroll
  for (int qt = 0; qt < 2; ++qt)
#pragma unroll
    for (int d = 0; d < 4; ++d) accO[qt][d] = (f32x4){0.f, 0.f, 0.f, 0.f};
  float lacc[2] = {0.f, 0.f};

  const short* kg0 = k16 + base + (long)g * 1024 * kHd;
  const short* vg0 = vT16 + base + g * 1024;

  // Stage one 64-key tile for this wave's group into buffer `buf`.
  auto stage = [&](int kt, int buf) {
    const short* kg = kg0 + (long)kt * 64 * kHd;
    const short* vg = vg0 + kt * 64;
    short* Kb = &smem[(g * 2 + buf) * 4096];
    short* Vb = &smem[(4 + g * 2 + buf) * 4096];
#pragma unroll
    for (int c = 0; c < 2; ++c) {       // K: 64 rows x 128B, 4 waves/group
      const int r0 = sw * 16 + c * 8;
      gl_lds16(kg + (long)(r0 + lrow8) * kHd + (lch8 ^ ((r0 + lrow8) & 7)) * 8,
               &Kb[r0 * 64]);
    }
#pragma unroll
    for (int c = 0; c < 2; ++c) {       // V: 64 dh-rows x 128B
      const int r0 = sw * 16 + c * 8;
      gl_lds16(vg + (long)(r0 + lrow8) * kN + (lch8 ^ ((r0 + lrow8) & 7)) * 8,
               &Vb[r0 * 64]);
    }
  };

  // Compute one 64-key tile from buffer `buf`.
  auto compute = [&](int buf) {
    const short* Kc = &smem[(g * 2 + buf) * 4096];
    const short* Vc = &smem[(4 + g * 2 + buf) * 4096];

    // QK^T swapped: sc[qt][t] = S^T tile, col = q (k15), row = key (quad*4+r).
    f32x4 sc[2][4];
    __builtin_amdgcn_s_setprio(1);
#pragma unroll
    for (int t = 0; t < 4; ++t) {
      const int row = t * 16 + k15;
      bf16x8 kb0 = *(const bf16x8*)&Kc[row * 64 + ((quad)     ^ (row & 7)) * 8];
      bf16x8 kb1 = *(const bf16x8*)&Kc[row * 64 + ((4 + quad) ^ (row & 7)) * 8];
      f32x4 z0 = {0.f, 0.f, 0.f, 0.f};
      z0 = __builtin_amdgcn_mfma_f32_16x16x32_bf16(kb0, qf[0][0], z0, 0, 0, 0);
      z0 = __builtin_amdgcn_mfma_f32_16x16x32_bf16(kb1, qf[0][1], z0, 0, 0, 0);
      sc[0][t] = z0;
      f32x4 z1 = {0.f, 0.f, 0.f, 0.f};
      z1 = __builtin_amdgcn_mfma_f32_16x16x32_bf16(kb0, qf[1][0], z1, 0, 0, 0);
      z1 = __builtin_amdgcn_mfma_f32_16x16x32_bf16(kb1, qf[1][1], z1, 0, 0, 0);
      sc[1][t] = z1;
    }
    __builtin_amdgcn_s_setprio(0);

    // exp2 + RNE pack to bf16 pairs; lane-local row-sum accumulation.
    unsigned pk[2][4][2];
#pragma unroll
    for (int qt = 0; qt < 2; ++qt) {
      float ls = 0.f;
#pragma unroll
      for (int t = 0; t < 4; ++t) {
        const float p0 = EXP2(sc[qt][t][0]);
        const float p1 = EXP2(sc[qt][t][1]);
        const float p2 = EXP2(sc[qt][t][2]);
        const float p3 = EXP2(sc[qt][t][3]);
        ls += (p0 + p1) + (p2 + p3);
        asm("v_cvt_pk_bf16_f32 %0, %1, %2" : "=v"(pk[qt][t][0]) : "v"(p0), "v"(p1));
        asm("v_cvt_pk_bf16_f32 %0, %1, %2" : "=v"(pk[qt][t][1]) : "v"(p2), "v"(p3));
      }
      lacc[qt] += ls;
    }

#pragma unroll
    for (int kc = 0; kc < 2; ++kc) {
      // Redistribute so lane (quad,q) holds keys kc*32 + quad*8 + {0..7}.
      union { unsigned u[4]; bf16x8 v; } pf[2];
#pragma unroll
      for (int qt = 0; qt < 2; ++qt) {
        unsigned a = pk[qt][2 * kc][0],     b = pk[qt][2 * kc][1];
        unsigned c = pk[qt][2 * kc + 1][0], d4 = pk[qt][2 * kc + 1][1];
        asm("v_permlane32_swap_b32 %0, %1" : "+v"(a), "+v"(c));
        asm("v_permlane16_swap_b32 %0, %1" : "+v"(a), "+v"(c));
        asm("v_permlane32_swap_b32 %0, %1" : "+v"(b), "+v"(d4));
        asm("v_permlane16_swap_b32 %0, %1" : "+v"(b), "+v"(d4));
        pf[qt].u[0] = a; pf[qt].u[1] = b; pf[qt].u[2] = c; pf[qt].u[3] = d4;
      }
      __builtin_amdgcn_s_setprio(1);
#pragma unroll
      for (int d = 0; d < 4; ++d) {
        const int vrow = d * 16 + k15;
        const int ch = (kc * 4 + quad) ^ (vrow & 7);
        bf16x8 vb = *(const bf16x8*)&Vc[vrow * 64 + ch * 8];
        accO[0][d] = __builtin_amdgcn_mfma_f32_16x16x32_bf16(pf[0].v, vb, accO[0][d], 0, 0, 0);
        accO[1][d] = __builtin_amdgcn_mfma_f32_16x16x32_bf16(pf[1].v, vb, accO[1][d], 0, 0, 0);
      }
      __builtin_amdgcn_s_setprio(0);
    }
  };

  stage(0, 0);
  __syncthreads();
  for (int kt = 0; kt < 16; ++kt) {
    if (kt + 1 < 16) stage(kt + 1, (kt + 1) & 1);   // prefetch under compute
    compute(kt & 1);
    __syncthreads();
  }

  // Per-wave partial row sums: lane (quad,q) holds 1/4 of its group's L[q].
  float s[2];
#pragma unroll
  for (int qt = 0; qt < 2; ++qt) {
    float v = lacc[qt];
    v += __shfl_xor(v, 16);
    v += __shfl_xor(v, 32);
    s[qt] = v;                      // L_partial[q = k15], replicated over quads
  }

  // In-block merge: group-1 waves publish (O, L) partials; group-0 adds,
  // normalizes, stores. Slot: 8 KiB accO + 512 B L per q-subwave.
  // The loop-final __syncthreads already fenced the last compute's reads.
  {
    char* slot = (char*)smem + sw * 8704;
    f32x4* so = (f32x4*)slot;
    float* sl = (float*)(slot + 8192);
    if (w >= 4) {
#pragma unroll
      for (int qt = 0; qt < 2; ++qt) {
#pragma unroll
        for (int d = 0; d < 4; ++d) so[(qt * 4 + d) * 64 + lane] = accO[qt][d];
        sl[qt * 64 + lane] = s[qt];
      }
    }
    __syncthreads();
    if (w < 4) {
#pragma unroll
      for (int qt = 0; qt < 2; ++qt) {
        f32x4 am[4];
#pragma unroll
        for (int d = 0; d < 4; ++d)
          am[d] = accO[qt][d] + so[(qt * 4 + d) * 64 + lane];
        const float Lsum = s[qt] + sl[qt * 64 + lane];   // L[q=k15]
#pragma unroll
        for (int r = 0; r < 4; ++r) {
          const float Ls = __shfl(Lsum, quad * 4 + r);   // lanes 0..15 hold q
          const float in = 1.f / Ls;
          const int gq = blockIdx.x * 128 + sw * 32 + qt * 16 + quad * 4 + r;
          short* drow = ao16 + ((long)(blockIdx.z * kN + gq)) * kDim + blockIdx.y * kHd;
#pragma unroll
          for (int d = 0; d < 4; ++d)
            drow[d * 16 + k15] = (short)f2bf(am[d][r] * in);
        }
      }
    }
  }
}

// ---------------------------------------------------------------------------
// Path C fallback (proven r3-style, 20 MiB): fp32-input VGPR-staged kernels.
__global__ __launch_bounds__(256, 2) void r3_qkv_kernel(
    const float* __restrict__ X, const float* __restrict__ W,
    short* __restrict__ q16, short* __restrict__ k16, short* __restrict__ v16) {
  __shared__ short As[128 * kP];
  __shared__ short Ws[128 * kP];
  const int tid  = threadIdx.x;
  const int w    = tid >> 6;
  const int lane = tid & 63;
  const int quad = lane >> 4;
  const int k15  = lane & 15;
  const int m0 = blockIdx.x * 128;
  const int n0 = blockIdx.y * 128;
  const int wm = (w >> 1) * 64;
  const int wn = (w & 1) * 64;

  f32x4 acc[4][4];
#pragma unroll
  for (int i = 0; i < 4; ++i)
#pragma unroll
    for (int j = 0; j < 4; ++j) acc[i][j] = (f32x4){0.f, 0.f, 0.f, 0.f};

  for (int kt = 0; kt < kDim; kt += 64) {
    __syncthreads();
#pragma unroll
    for (int p = 0; p < 8; ++p) {
      const int idx = p * 256 + tid;
      const int row = idx >> 4;
      const int c4  = (idx & 15) << 2;
      float4 av = *(const float4*)&X[(long)(m0 + row) * kDim + kt + c4];
      uint2 ap = {pack2bf(av.x, av.y), pack2bf(av.z, av.w)};
      *(uint2*)&As[row * kP + c4] = ap;
      float4 wv = *(const float4*)&W[(long)(n0 + row) * kDim + kt + c4];
      uint2 wp = {pack2bf(wv.x, wv.y), pack2bf(wv.z, wv.w)};
      *(uint2*)&Ws[row * kP + c4] = wp;
    }
    __syncthreads();
#pragma unroll
    for (int ks = 0; ks < 2; ++ks) {
      bf16x8 af[4], bf[4];
#pragma unroll
      for (int t = 0; t < 4; ++t) {
        af[t] = *(const bf16x8*)&As[(wm + t * 16 + k15) * kP + ks * 32 + quad * 8];
        bf[t] = *(const bf16x8*)&Ws[(wn + t * 16 + k15) * kP + ks * 32 + quad * 8];
      }
#pragma unroll
      for (int mt = 0; mt < 4; ++mt)
#pragma unroll
        for (int nt = 0; nt < 4; ++nt)
          acc[mt][nt] = __builtin_amdgcn_mfma_f32_16x16x32_bf16(
              af[mt], bf[nt], acc[mt][nt], 0, 0, 0);
    }
  }

  const int t_sel = n0 >> 10;
  short* dst = (t_sel == 0) ? q16 : (t_sel == 1) ? k16 : v16;
  const float scl = (t_sel == 0) ? kScale : 1.0f;
#pragma unroll
  for (int nt = 0; nt < 4; ++nt) {
    const int d  = n0 + wn + nt * 16 + k15;
    const int h  = (d >> 6) & 15;
    const int dh = d & 63;
#pragma unroll
    for (int mt = 0; mt < 4; ++mt) {
#pragma unroll
      for (int r = 0; r < 4; ++r) {
        const int m = m0 + wm + mt * 16 + quad * 4 + r;
        dst[((long)h * kN + m) * kHd + dh] = (short)f2bf(acc[mt][nt][r] * scl);
      }
    }
  }
}

__global__ __launch_bounds__(256, 4) void attn_v1_kernel(
    const short* __restrict__ q16, const short* __restrict__ k16,
    const short* __restrict__ v16, short* __restrict__ ao16, int bpar) {
  __shared__ short Ks[64 * kP];
  __shared__ short Vs[64 * kP];
  __shared__ short Ps[4 * 16 * kP];
  const int tid  = threadIdx.x;
  const int w    = tid >> 6;
  const int lane = tid & 63;
  const int quad = lane >> 4;
  const int k15  = lane & 15;
  const long base = (long)blockIdx.y * kN * kHd;
  const int qrow = blockIdx.x * 64 + w * 16 + k15;
  const short* qp = q16 + base + (long)qrow * kHd + quad * 8;
  bf16x8 qf0 = *(const bf16x8*)(qp);
  bf16x8 qf1 = *(const bf16x8*)(qp + 32);

  f32x4 accO[4] = {{0.f,0.f,0.f,0.f},{0.f,0.f,0.f,0.f},
                   {0.f,0.f,0.f,0.f},{0.f,0.f,0.f,0.f}};
  float lsum[4] = {0.f, 0.f, 0.f, 0.f};

  for (int kt = 0; kt < kN / 64; ++kt) {
    __syncthreads();
    {
      const short* kg = k16 + base + (long)kt * 64 * kHd;
      const short* vg = v16 + base + (long)kt * 64 * kHd;
#pragma unroll
      for (int p = 0; p < 2; ++p) {
        const int idx = p * 256 + tid;
        const int key = idx >> 3;
        const int c8  = (idx & 7) << 3;
        *(bf16x8*)&Ks[key * kP + c8] = *(const bf16x8*)&kg[key * kHd + c8];
        bf16x8 vv = *(const bf16x8*)&vg[key * kHd + c8];
#pragma unroll
        for (int j = 0; j < 8; ++j) Vs[(c8 + j) * kP + key] = vv[j];
      }
    }
    __syncthreads();

    f32x4 sc[4];
#pragma unroll
    for (int t = 0; t < 4; ++t) {
      bf16x8 kb0 = *(const bf16x8*)&Ks[(t * 16 + k15) * kP + quad * 8];
      bf16x8 kb1 = *(const bf16x8*)&Ks[(t * 16 + k15) * kP + 32 + quad * 8];
      f32x4 z = {0.f, 0.f, 0.f, 0.f};
      z = __builtin_amdgcn_mfma_f32_16x16x32_bf16(qf0, kb0, z, 0, 0, 0);
      z = __builtin_amdgcn_mfma_f32_16x16x32_bf16(qf1, kb1, z, 0, 0, 0);
      sc[t] = z;
    }
    short* pw = &Ps[w * (16 * kP)];
#pragma unroll
    for (int t = 0; t < 4; ++t) {
#pragma unroll
      for (int r = 0; r < 4; ++r) {
        const float p = __expf(sc[t][r]);
        lsum[r] += p;
        pw[(quad * 4 + r) * kP + t * 16 + k15] = (short)f2bf(p);
      }
    }
    bf16x8 pf0 = *(const bf16x8*)&pw[k15 * kP + quad * 8];
    bf16x8 pf1 = *(const bf16x8*)&pw[k15 * kP + 32 + quad * 8];
#pragma unroll
    for (int t = 0; t < 4; ++t) {
      bf16x8 vb0 = *(const bf16x8*)&Vs[(t * 16 + k15) * kP + quad * 8];
      bf16x8 vb1 = *(const bf16x8*)&Vs[(t * 16 + k15) * kP + 32 + quad * 8];
      accO[t] = __builtin_amdgcn_mfma_f32_16x16x32_bf16(pf0, vb0, accO[t], 0, 0, 0);
      accO[t] = __builtin_amdgcn_mfma_f32_16x16x32_bf16(pf1, vb1, accO[t], 0, 0, 0);
    }
  }

#pragma unroll
  for (int r = 0; r < 4; ++r) {
    float s = lsum[r];
    s += __shfl_xor(s, 1);
    s += __shfl_xor(s, 2);
    s += __shfl_xor(s, 4);
    s += __shfl_xor(s, 8);
    lsum[r] = 1.f / s;
  }
#pragma unroll
  for (int r = 0; r < 4; ++r) {
    const int gq = blockIdx.x * 64 + w * 16 + quad * 4 + r;
    short* drow = ao16 + ((long)(bpar * kN + gq)) * kDim + blockIdx.y * kHd;
#pragma unroll
    for (int t = 0; t < 4; ++t)
      drow[t * 16 + k15] = (short)f2bf(accO[t][r] * lsum[r]);
  }
}

__global__ __launch_bounds__(256, 2) void r3_proj_kernel(
    const short* __restrict__ A16, const float* __restrict__ W,
    const float* __restrict__ bias, float* __restrict__ out) {
  __shared__ short As[128 * kP];
  __shared__ short Ws[128 * kP];
  const int tid  = threadIdx.x;
  const int w    = tid >> 6;
  const int lane = tid & 63;
  const int quad = lane >> 4;
  const int k15  = lane & 15;
  const int m0 = blockIdx.x * 128;
  const int n0 = blockIdx.y * 128;
  const int wm = (w >> 1) * 64;
  const int wn = (w & 1) * 64;

  f32x4 acc[4][4];
#pragma unroll
  for (int i = 0; i < 4; ++i)
#pragma unroll
    for (int j = 0; j < 4; ++j) acc[i][j] = (f32x4){0.f, 0.f, 0.f, 0.f};

  for (int kt = 0; kt < kDim; kt += 64) {
    __syncthreads();
#pragma unroll
    for (int p = 0; p < 4; ++p) {
      const int idx = p * 256 + tid;
      const int row = idx >> 3;
      const int c8  = (idx & 7) << 3;
      *(bf16x8*)&As[row * kP + c8] =
          *(const bf16x8*)&A16[(long)(m0 + row) * kDim + kt + c8];
    }
#pragma unroll
    for (int p = 0; p < 8; ++p) {
      const int idx = p * 256 + tid;
      const int row = idx >> 4;
      const int c4  = (idx & 15) << 2;
      float4 wv = *(const float4*)&W[(long)(n0 + row) * kDim + kt + c4];
      uint2 wp = {pack2bf(wv.x, wv.y), pack2bf(wv.z, wv.w)};
      *(uint2*)&Ws[row * kP + c4] = wp;
    }
    __syncthreads();
#pragma unroll
    for (int ks = 0; ks < 2; ++ks) {
      bf16x8 af[4], bf[4];
#pragma unroll
      for (int t = 0; t < 4; ++t) {
        af[t] = *(const bf16x8*)&As[(wm + t * 16 + k15) * kP + ks * 32 + quad * 8];
        bf[t] = *(const bf16x8*)&Ws[(wn + t * 16 + k15) * kP + ks * 32 + quad * 8];
      }
#pragma unroll
      for (int mt = 0; mt < 4; ++mt)
#pragma unroll
        for (int nt = 0; nt < 4; ++nt)
          acc[mt][nt] = __builtin_amdgcn_mfma_f32_16x16x32_bf16(
              af[mt], bf[nt], acc[mt][nt], 0, 0, 0);
    }
  }

#pragma unroll
  for (int nt = 0; nt < 4; ++nt) {
    const int d = n0 + wn + nt * 16 + k15;
    const float bb = bias[d];
#pragma unroll
    for (int mt = 0; mt < 4; ++mt) {
#pragma unroll
      for (int r = 0; r < 4; ++r) {
        const int m = m0 + wm + mt * 16 + quad * 4 + r;
        out[(long)m * kDim + d] = acc[mt][nt][r] + bb;
      }
    }
  }
}

// ---------------------------------------------------------------------------
extern "C" void kernel_launch(void* const* d_in, const int* in_sizes, int n_in,
                              void* d_out, int out_size, void* d_ws, size_t ws_size,
                              hipStream_t stream) {
  const float* x      = (const float*)d_in[0];
  const float* qkv_w  = (const float*)d_in[1];
  const float* proj_w = (const float*)d_in[2];
  const float* proj_b = (const float*)d_in[3];
  float* out = (float*)d_out;

  short* ws = (short*)d_ws;
  const size_t MiS = 1048576;

  if (ws_size >= 41943040ull) {
    // Path A (40 MiB): X16 aliased with ao.
    short* X16  = ws;              // [4096,1024]
    short* W16  = ws + 4 * MiS;    // [3072,1024]
    short* PW16 = ws + 7 * MiS;    // [1024,1024]
    short* q16  = ws + 8 * MiS;    // [2][16][2048][64]
    short* k16  = ws + 12 * MiS;   // [2][16][2048][64]
    short* vT16 = ws + 16 * MiS;   // [2][16][64][2048]
    short* ao16 = X16;

    cvt3_kernel<<<4096, 256, 0, stream>>>(x, X16, 2048, qkv_w, W16, 1536,
                                          proj_w, PW16);
    mm_qkv_kernel<<<768, 256, 0, stream>>>(X16, W16, q16, k16, vT16);
    attn_kernel<<<dim3(16, 16, 2), 512, 0, stream>>>(q16, k16, vT16, ao16);
    mm_proj_kernel<<<512, 256, 0, stream>>>(ao16, PW16, proj_b, out);
    return;
  }

  // Path C fallback (20 MiB, proven structure).
  {
    short* q16  = ws;
    short* k16  = ws + 2 * MiS;
    short* v16  = ws + 4 * MiS;
    short* ao16 = ws + 6 * MiS;
    for (int b = 0; b < kB; ++b) {
      r3_qkv_kernel<<<dim3(16, 24), 256, 0, stream>>>(
          x + (size_t)b * kN * kDim, qkv_w, q16, k16, v16);
      attn_v1_kernel<<<dim3(32, 16), 256, 0, stream>>>(q16, k16, v16, ao16, b);
    }
    r3_proj_kernel<<<dim3(32, 8), 256, 0, stream>>>(ao16, proj_w, proj_b, out);
  }
}